// Round 8
// baseline (441.151 us; speedup 1.0000x reference)
//
#include <hip/hip_runtime.h>
#include <stdint.h>

typedef unsigned short u16;
typedef __bf16 v8bf __attribute__((ext_vector_type(8)));
typedef float  v4f  __attribute__((ext_vector_type(4)));

__device__ __forceinline__ u16 f2bf(float f) {
    union { float f; unsigned u; } x; x.f = f;
    unsigned r = (x.u + 0x7FFFu + ((x.u >> 16) & 1u)) >> 16;
    return (u16)r;
}
__device__ __forceinline__ unsigned pkbf(float a, float b) {
    return (unsigned)f2bf(a) | ((unsigned)f2bf(b) << 16);
}
__device__ __forceinline__ float sigf(float x) { return 1.f / (1.f + __expf(-x)); }
__device__ __forceinline__ void gload(const u16* src, u16* ldst) {
    __builtin_amdgcn_global_load_lds((const __attribute__((address_space(1))) void*)src,
                                     (__attribute__((address_space(3))) void*)ldst, 16, 0, 0);
}

// ---------------- workspace layout (bytes) ----------------
#define OFF_XINBF  0UL            // u16 [10240][192]
#define OFF_XG     3932160UL      // f32 [10240][768]
#define OFF_FC1    44728320UL     // f32 [1280][256]
#define OFF_WB1    125829120UL    // u16 [1024][6144]
#define OFF_C1     138412032UL    // u16 [10240][1024]
#define OFF_WB2    159383552UL    // u16 [256][1024]
#define OFF_WB3    165150720UL    // u16 [128][256] (rows 64..127 zero)
#define OFF_BFE    165216256UL    // f32 [10240][64]
#define OFF_OFE    167837696UL    // f32 [10240][64]
#define OFF_MFE    170459136UL    // f32 [10240][64]
#define OFF_WIH    173095936UL    // u16 [768][192]
#define OFF_WHH    173390848UL    // u16 [768][192]
#define OFF_WF1    173685760UL    // u16 [256][1536]
#define OFF_BSUM   174472192UL    // f32 [768]  (bih+bhh)

// ---------------- weight conversions (one grid-stride kernel) ----------------
__global__ void __launch_bounds__(256) conv_weights(
    const float* __restrict__ Wb1, const float* __restrict__ Wb2, const float* __restrict__ Wb3,
    const float* __restrict__ Wih, const float* __restrict__ Whh, const float* __restrict__ Wf1,
    const float* __restrict__ bih, const float* __restrict__ bhh,
    u16* __restrict__ dWb1, u16* __restrict__ dWb2, u16* __restrict__ dWb3,
    u16* __restrict__ dWih, u16* __restrict__ dWhh, u16* __restrict__ dWf1,
    float* __restrict__ bsum)
{
    const long C0 = 6291456, C1 = 6553600, C2 = 6586368, C3 = 6733824,
               C4 = 6881280, C5 = 7274496, C6 = 7275264;
    for (long i = (long)blockIdx.x * 256 + threadIdx.x; i < C6; i += (long)gridDim.x * 256) {
        if (i < C0) {
            int r = (int)(i / 6144), k = (int)(i % 6144);
            dWb1[i] = f2bf(k < 6075 ? Wb1[(long)r * 6075 + k] : 0.f);
        } else if (i < C1) {
            long j = i - C0;
            dWb2[j] = f2bf(Wb2[j]);
        } else if (i < C2) {
            long j = i - C1;
            dWb3[j] = f2bf(j < 16384 ? Wb3[j] : 0.f);
        } else if (i < C3) {
            long j = i - C2;
            dWih[j] = f2bf(Wih[j]);
        } else if (i < C4) {
            long j = i - C3;
            dWhh[j] = f2bf(Whh[j]);
        } else if (i < C5) {
            long j = i - C4;
            dWf1[j] = f2bf(Wf1[j]);
        } else {
            long j = i - C5;
            bsum[j] = bih[j] + bhh[j];
        }
    }
}

// ---------------- L1 GEMM with FUSED f32->bf16 board conversion ----------------
// BM=160 x BN=128, 256 thr (4 waves, 80x64 each), grid 512 = 2 blocks/CU.
// A is read as f32 from `board` [10240][6075] directly (reg-staged, T14 split:
// loads issued at iter head, cvt+swizzled ds_write after barrier-2), eliminating
// the conv_board pass (saves ~250MB of HBM round-trip). B keeps global_load_lds.
// XCD mapping: 8 col-blocks of a row-panel on ONE XCD -> A f32 re-reads are L2-hits.
#define G160_LDS 73728
__global__ void __launch_bounds__(256, 2)
gemm160f(const float* __restrict__ A32, const u16* __restrict__ B,
         const float* __restrict__ bias, u16* __restrict__ C, int K)
{
    extern __shared__ __align__(16) u16 smem[];   // [2][A 160x64 bf16 | B 128x64]
    const int tid = threadIdx.x, wv = tid >> 6, lane = tid & 63;
    const int bid = blockIdx.x;
    const int k8 = bid & 7;                  // XCD id
    const int j  = bid >> 3;                 // 0..63
    const int rowt = k8 + (j >> 3) * 8;      // row-tile pinned to XCD
    const int col  = j & 7;
    const long m0 = (long)rowt * 160;
    const long n0 = (long)col * 128;

    const int sr8 = lane >> 3;
    const int sslot = (lane & 7) ^ sr8;
    const u16* Bg = B + (n0 + wv * 8 + sr8) * (long)K + sslot * 8;
    const int wr = wv >> 1, wc = wv & 1;
    const int wm = wr * 80, wn = wc * 64;
    const int fr = lane & 15, hi = lane >> 4, fx = fr & 7;

    const int nk = K >> 6;                   // 96

    // A-staging thread geometry: thread owns rows q*16+(tid>>4), cols (tid&15)*4..+3
    const int arow0 = tid >> 4;              // 0..15
    const int col4  = tid & 15;
    const float* pa[10];
#pragma unroll
    for (int q = 0; q < 10; ++q)
        pa[q] = A32 + (m0 + q * 16 + arow0) * 6075L + col4 * 4;
    // swizzled LDS write offset (elem units); slot = col4>>1, pos = slot ^ (row&7)
    const int awbase = arow0 * 64 + (((col4 >> 1) ^ (arow0 & 7)) * 8) + (col4 & 1) * 4;

    float R[40];
    auto AL = [&](int tile) {
        if (tile < 94) {
#pragma unroll
            for (int q = 0; q < 10; ++q) {
#pragma unroll
                for (int jj = 0; jj < 4; ++jj) R[q * 4 + jj] = pa[q][jj];
                pa[q] += 64;
            }
        } else {
            int kb = tile * 64 + col4 * 4;
#pragma unroll
            for (int q = 0; q < 10; ++q) {
#pragma unroll
                for (int jj = 0; jj < 4; ++jj) {
                    float v = 0.f;
                    if (kb + jj < 6075) v = pa[q][jj];
                    R[q * 4 + jj] = v;
                }
                pa[q] += 64;
            }
        }
    };
    auto AWRITE = [&](int bufofs) {
#pragma unroll
        for (int q = 0; q < 10; ++q) {
            uint2 w;
            w.x = pkbf(R[q * 4 + 0], R[q * 4 + 1]);
            w.y = pkbf(R[q * 4 + 2], R[q * 4 + 3]);
            *(uint2*)(smem + bufofs + awbase + q * 1024) = w;
        }
    };
    auto SB = [&](int buf, int t) {
        const long k0 = (long)t * 64;
        const int ab = buf * 18432 + 10240;
#pragma unroll
        for (int r = 0; r < 4; ++r)
            gload(Bg + (long)r * 32 * K + k0, smem + ab + r * 2048 + wv * 512);
    };
    auto LDA_ = [&](int buf, int ks, int i) -> v8bf {
        return *(const v8bf*)(smem + buf * 18432 + (wm + i * 16 + fr) * 64 + ((ks * 4 + hi) ^ fx) * 8);
    };
    auto LDB_ = [&](int buf, int ks, int j2) -> v8bf {
        return *(const v8bf*)(smem + buf * 18432 + 10240 + (wn + j2 * 16 + fr) * 64 + ((ks * 4 + hi) ^ fx) * 8);
    };

    v4f acc[5][4] = {};

    // prologue: B DMA for tiles 0,1; A tile 0 load+convert+write
    SB(0, 0);
    SB(1, 1);
    AL(0);
    asm volatile("s_waitcnt vmcnt(8)" ::: "memory");   // A(0) done; B0,B1 in flight
    AWRITE(0);

    for (int t = 0; t < nk; ++t) {
        const int buf = t & 1;
        // head: B(t) was confirmed at t-1 tail; A(t) writes drain here
        asm volatile("s_waitcnt vmcnt(4) lgkmcnt(0)" ::: "memory");
        asm volatile("s_barrier" ::: "memory");
        if (t + 1 < nk) AL(t + 1);           // issue next A loads: full iter of cover
        __builtin_amdgcn_sched_barrier(0);
        __builtin_amdgcn_s_setprio(1);
        v8bf a0[5], a1[5], b0[4], b1[4];
        // P0: 9 reads (ks0)
#pragma unroll
        for (int j2 = 0; j2 < 4; ++j2) b0[j2] = LDB_(buf, 0, j2);
#pragma unroll
        for (int i = 0; i < 5; ++i) a0[i] = LDA_(buf, 0, i);
        __builtin_amdgcn_sched_barrier(0);
        // P1: 9 reads (ks1) + 20 MFMA (ks0)
#pragma unroll
        for (int j2 = 0; j2 < 4; ++j2) b1[j2] = LDB_(buf, 1, j2);
#pragma unroll
        for (int i = 0; i < 5; ++i) a1[i] = LDA_(buf, 1, i);
#pragma unroll
        for (int i = 0; i < 5; ++i)
#pragma unroll
            for (int j2 = 0; j2 < 4; ++j2)
                acc[i][j2] = __builtin_amdgcn_mfma_f32_16x16x32_bf16(a0[i], b0[j2], acc[i][j2], 0, 0, 0);
        __builtin_amdgcn_sched_barrier(0);
        __builtin_amdgcn_s_setprio(0);
        asm volatile("s_waitcnt lgkmcnt(0)" ::: "memory");
        __builtin_amdgcn_sched_barrier(0);
        asm volatile("s_barrier" ::: "memory");
        // tail: issue next B DMA, then convert+write A(t+1) into buf^1
        if (t + 2 < nk) SB(buf, t + 2);
        if (t + 1 < nk) {
            if (t + 2 < nk) { asm volatile("s_waitcnt vmcnt(4)" ::: "memory"); }
            else            { asm volatile("s_waitcnt vmcnt(0)" ::: "memory"); }
            AWRITE((buf ^ 1) * 18432);
        }
        __builtin_amdgcn_sched_barrier(0);
        // P2: 20 register-only MFMA (ks1) covering STAGE/convert
        __builtin_amdgcn_s_setprio(1);
#pragma unroll
        for (int i = 0; i < 5; ++i)
#pragma unroll
            for (int j2 = 0; j2 < 4; ++j2)
                acc[i][j2] = __builtin_amdgcn_mfma_f32_16x16x32_bf16(a1[i], b1[j2], acc[i][j2], 0, 0, 0);
        __builtin_amdgcn_s_setprio(0);
    }

#pragma unroll
    for (int i = 0; i < 5; ++i) {
        const long mr = m0 + wm + i * 16 + hi * 4;
#pragma unroll
        for (int j2 = 0; j2 < 4; ++j2) {
            const long n = n0 + wn + j2 * 16 + fr;
            float bv = bias[n];
#pragma unroll
            for (int r = 0; r < 4; ++r) {
                float v = fmaxf(acc[i][j2][r] + bv, 0.f);
                C[(mr + r) * 1024L + n] = f2bf(v);
            }
        }
    }
}

// ---------------- L2 GEMM (BM=128 BN=256 K=1024) with fused L3 epilogue ------------
#define L23_LDS 98304
__global__ void __launch_bounds__(512, 1)
gemm_l23(const u16* __restrict__ A, const u16* __restrict__ B, const float* __restrict__ b2,
         const u16* __restrict__ W3, const float* __restrict__ b3, float* __restrict__ Out)
{
    extern __shared__ __align__(16) u16 smem[];
    const int tid = threadIdx.x, wv = tid >> 6, lane = tid & 63;
    const long m0 = (long)blockIdx.x * 128;
    const int sr8 = lane >> 3;
    const int sslot = (lane & 7) ^ sr8;
    const u16* Ag = A + (m0 + wv * 8 + sr8) * 1024L + sslot * 8;
    const u16* Bg = B + (wv * 8 + sr8) * 1024L + sslot * 8;
    const int wr = wv >> 2, wc = wv & 3;
    const int wm = wr * 64, wn = wc * 64;
    const int fr = lane & 15, hi = lane >> 4, fx = fr & 7;

    v4f acc[4][4] = {};

    auto STAGE = [&](int buf, int t) {
        const long k0 = (long)t * 64;
        const int ab = buf * 24576;
#pragma unroll
        for (int r = 0; r < 2; ++r)
            gload(Ag + (long)r * 64 * 1024 + k0, smem + ab + r * 4096 + wv * 512);
#pragma unroll
        for (int r = 0; r < 4; ++r)
            gload(Bg + (long)r * 64 * 1024 + k0, smem + ab + 8192 + r * 4096 + wv * 512);
    };
    auto COMPUTE = [&](int buf) {
#pragma unroll
        for (int ks = 0; ks < 2; ++ks) {
            const int sw = ((ks * 4 + hi) ^ fx) * 8;
            v8bf a[4], b[4];
#pragma unroll
            for (int i = 0; i < 4; ++i)
                a[i] = *(const v8bf*)(smem + buf * 24576 + (wm + i * 16 + fr) * 64 + sw);
#pragma unroll
            for (int j = 0; j < 4; ++j)
                b[j] = *(const v8bf*)(smem + buf * 24576 + 8192 + (wn + j * 16 + fr) * 64 + sw);
#pragma unroll
            for (int i = 0; i < 4; ++i)
#pragma unroll
                for (int j = 0; j < 4; ++j)
                    acc[i][j] = __builtin_amdgcn_mfma_f32_16x16x32_bf16(a[i], b[j], acc[i][j], 0, 0, 0);
        }
    };

    STAGE(0, 0);
    __syncthreads();
    int t = 1;
    while (true) {
        if (t < 16) STAGE(1, t);
        COMPUTE(0);
        if (t >= 16) break;
        __syncthreads();
        ++t;
        if (t < 16) STAGE(0, t);
        COMPUTE(1);
        if (t >= 16) break;
        __syncthreads();
        ++t;
    }
    __syncthreads();
    u16* C2s = smem;
#pragma unroll
    for (int i = 0; i < 4; ++i) {
        const int rrow = wm + i * 16 + hi * 4;
#pragma unroll
        for (int j = 0; j < 4; ++j) {
            const int ccol = wn + j * 16 + fr;
            float bv = b2[ccol];
#pragma unroll
            for (int r = 0; r < 4; ++r)
                C2s[(rrow + r) * 264 + ccol] = f2bf(fmaxf(acc[i][j][r] + bv, 0.f));
        }
    }
    __syncthreads();
    v4f a3[4] = {};
#pragma unroll
    for (int kk = 0; kk < 8; ++kk) {
        v8bf af = *(const v8bf*)(&C2s[(wv * 16 + fr) * 264 + kk * 32 + hi * 8]);
#pragma unroll
        for (int j = 0; j < 4; ++j) {
            v8bf bfr = *(const v8bf*)(W3 + (j * 16 + fr) * 256 + kk * 32 + hi * 8);
            a3[j] = __builtin_amdgcn_mfma_f32_16x16x32_bf16(af, bfr, a3[j], 0, 0, 0);
        }
    }
#pragma unroll
    for (int j = 0; j < 4; ++j) {
        int n = j * 16 + fr;
        float bv = b3[n];
#pragma unroll
        for (int q = 0; q < 4; ++q)
            Out[(m0 + wv * 16 + hi * 4 + q) * 64 + n] = a3[j][q] + bv;
    }
}

// ---------------- bf16 MFMA GEMM 128x128 (used for Xg only) ----------------
template<int OBF, int RELU, int BIAS>
__global__ void __launch_bounds__(256)
gemm_bt(const u16* __restrict__ A, const u16* __restrict__ B,
        const float* __restrict__ bias, void* __restrict__ Cv,
        int M, int N, int K, int ldc)
{
    __shared__ __align__(16) u16 As[2][128 * 64];
    __shared__ __align__(16) u16 Bs[2][128 * 64];
    const int tid = threadIdx.x;
    const int wv = tid >> 6, lane = tid & 63;
    const long m0 = (long)blockIdx.y * 128;
    const long n0 = (long)blockIdx.x * 128;
    const int srow  = wv * 8 + (lane >> 3);
    const int sslot = (lane & 7) ^ (lane >> 3);
    const u16* Ag = A + (m0 + srow) * (long)K + sslot * 8;
    const u16* Bg = B + (n0 + srow) * (long)K + sslot * 8;
    const int wm = (wv >> 1) * 64, wn = (wv & 1) * 64;
    const int fr = lane & 15, hi = lane >> 4;
    const int fx = fr & 7;

    v4f acc[4][4] = {};
    const int nk = K >> 6;

    auto STAGE = [&](int buf, int k0) {
#pragma unroll
        for (int r = 0; r < 4; ++r)
            gload(Ag + (long)r * 32 * K + k0, &As[buf][r * 2048 + wv * 512]);
#pragma unroll
        for (int r = 0; r < 4; ++r)
            gload(Bg + (long)r * 32 * K + k0, &Bs[buf][r * 2048 + wv * 512]);
    };
    auto COMPUTE = [&](int buf) {
#pragma unroll
        for (int ks = 0; ks < 2; ++ks) {
            v8bf a[4], b[4];
            const int sw = (((ks * 4 + hi) ^ fx)) * 8;
#pragma unroll
            for (int i = 0; i < 4; ++i)
                a[i] = *(const v8bf*)(&As[buf][(wm + i * 16 + fr) * 64 + sw]);
#pragma unroll
            for (int j = 0; j < 4; ++j)
                b[j] = *(const v8bf*)(&Bs[buf][(wn + j * 16 + fr) * 64 + sw]);
#pragma unroll
            for (int i = 0; i < 4; ++i)
#pragma unroll
                for (int j = 0; j < 4; ++j)
                    acc[i][j] = __builtin_amdgcn_mfma_f32_16x16x32_bf16(a[i], b[j], acc[i][j], 0, 0, 0);
        }
    };

    STAGE(0, 0);
    __syncthreads();
    int t = 1;
    while (true) {
        if (t < nk) STAGE(1, t * 64);
        COMPUTE(0);
        if (t >= nk) break;
        __syncthreads();
        ++t;
        if (t < nk) STAGE(0, t * 64);
        COMPUTE(1);
        if (t >= nk) break;
        __syncthreads();
        ++t;
    }

#pragma unroll
    for (int i = 0; i < 4; ++i) {
        const long mr = m0 + wm + i * 16 + hi * 4;
#pragma unroll
        for (int j = 0; j < 4; ++j) {
            const long n = n0 + wn + j * 16 + fr;
            if (n < N) {
                float bv = BIAS ? bias[n] : 0.f;
#pragma unroll
                for (int r = 0; r < 4; ++r) {
                    float v = acc[i][j][r] + bv;
                    if (RELU) v = fmaxf(v, 0.f);
                    if (OBF) ((u16*)Cv)[(mr + r) * (long)ldc + n] = f2bf(v);
                    else     ((float*)Cv)[(mr + r) * (long)ldc + n] = v;
                }
            }
        }
    }
}

// ---------------- small 3-layer MLP body (order/message), f32, LDS-resident ----------
template<int D0, int D1>
__device__ __forceinline__ void mlp3_body(
    float* sm, const float* __restrict__ X,
    const float* __restrict__ W1, const float* __restrict__ B1,
    const float* __restrict__ W2, const float* __restrict__ B2,
    const float* __restrict__ W3, const float* __restrict__ B3,
    float* __restrict__ Out, int blk)
{
    float* w1s = sm;
    float* w2s = w1s + D0 * D1;
    float* w3s = w2s + D1 * 32;
    float* b1s = w3s + 32 * 64;
    float* b2s = b1s + D1;
    float* b3s = b2s + 32;
    float* xs  = b3s + 64;
    float* h1  = xs + 32 * D0;
    float* h2  = h1 + 32 * D1;

    const int tid = threadIdx.x;
    const long row0 = (long)blk * 32;

    for (int i = tid; i < D0 * D1; i += 256) { int k = i / D1, n = i % D1; w1s[i] = W1[n * D0 + k]; }
    for (int i = tid; i < D1 * 32; i += 256) { int k = i / 32,  n = i % 32; w2s[i] = W2[n * D1 + k]; }
    for (int i = tid; i < 32 * 64; i += 256) { int k = i / 64,  n = i % 64; w3s[i] = W3[n * 32 + k]; }
    if (tid < D1) b1s[tid] = B1[tid];
    if (tid < 32) b2s[tid] = B2[tid];
    if (tid < 64) b3s[tid] = B3[tid];
    for (int i = tid; i < 32 * D0; i += 256) xs[i] = X[(row0 + i / D0) * D0 + i % D0];
    __syncthreads();

    const int wv = tid >> 6, lane = tid & 63;
    const int r0 = wv * 8;
    {
        constexpr int NL = D1 / 64;
        float acc[NL][8];
#pragma unroll
        for (int a = 0; a < NL; ++a)
#pragma unroll
            for (int r = 0; r < 8; ++r) acc[a][r] = 0.f;
        for (int k = 0; k < D0; ++k) {
            float w[NL];
#pragma unroll
            for (int a = 0; a < NL; ++a) w[a] = w1s[k * D1 + lane + a * 64];
#pragma unroll
            for (int r = 0; r < 8; ++r) {
                float x = xs[(r0 + r) * D0 + k];
#pragma unroll
                for (int a = 0; a < NL; ++a) acc[a][r] += w[a] * x;
            }
        }
#pragma unroll
        for (int a = 0; a < NL; ++a)
#pragma unroll
            for (int r = 0; r < 8; ++r)
                h1[(r0 + r) * D1 + lane + a * 64] = fmaxf(acc[a][r] + b1s[lane + a * 64], 0.f);
    }
    __syncthreads();
    {
        int n = lane & 31;
        int rb = r0 + (lane >> 5) * 4;
        float acc[4] = {0, 0, 0, 0};
        for (int k = 0; k < D1; ++k) {
            float w = w2s[k * 32 + n];
#pragma unroll
            for (int r = 0; r < 4; ++r) acc[r] += w * h1[(rb + r) * D1 + k];
        }
#pragma unroll
        for (int r = 0; r < 4; ++r) h2[(rb + r) * 32 + n] = fmaxf(acc[r] + b2s[n], 0.f);
    }
    __syncthreads();
    {
        float acc[8] = {};
        for (int k = 0; k < 32; ++k) {
            float w = w3s[k * 64 + lane];
#pragma unroll
            for (int r = 0; r < 8; ++r) acc[r] += w * h2[(r0 + r) * 32 + k];
        }
#pragma unroll
        for (int r = 0; r < 8; ++r) Out[(row0 + r0 + r) * 64 + lane] = acc[r] + b3s[lane];
    }
}

#define MLP_LDS 71552
__global__ void __launch_bounds__(256)
mlp3_dual(const float* __restrict__ Xo,
          const float* __restrict__ Wo1, const float* __restrict__ bo1,
          const float* __restrict__ Wo2, const float* __restrict__ bo2,
          const float* __restrict__ Wo3, const float* __restrict__ bo3,
          float* __restrict__ ofe,
          const float* __restrict__ Xm,
          const float* __restrict__ Wm1, const float* __restrict__ bm1,
          const float* __restrict__ Wm2, const float* __restrict__ bm2,
          const float* __restrict__ Wm3, const float* __restrict__ bm3,
          float* __restrict__ mfe)
{
    extern __shared__ __align__(16) float sm[];
    if (blockIdx.x < 320)
        mlp3_body<40, 128>(sm, Xo, Wo1, bo1, Wo2, bo2, Wo3, bo3, ofe, blockIdx.x);
    else
        mlp3_body<20, 64>(sm, Xm, Wm1, bm1, Wm2, bm2, Wm3, bm3, mfe, blockIdx.x - 320);
}

// ---------------- scramble + in-block BN stats + relu -> LSTM input (bf16) ------------
#define BX_LDS 100032
__global__ void __launch_bounds__(256, 1)
build_xin2(const float* __restrict__ bfe, const float* __restrict__ ofe, const float* __restrict__ mfe,
           const float* __restrict__ g1, const float* __restrict__ be1,
           const float* __restrict__ g2, const float* __restrict__ be2,
           const float* __restrict__ g3, const float* __restrict__ be3,
           u16* __restrict__ xin)
{
    extern __shared__ __align__(16) float ls[];   // [3][128][8][8]
    float* coefA = ls + 24576;
    float* coefB = coefA + 24;
    float* psum  = coefB + 24;
    float* psum2 = psum + 192;
    const int p = blockIdx.x >> 3, s = blockIdx.x & 7;
    const int tid = threadIdx.x;
    const float* Fs[3] = {bfe, ofe, mfe};
    for (int g = tid; g < 3072; g += 256) {
        int br = g >> 10, rr = g & 1023, bb = rr >> 3, tt = rr & 7;
        const float* srcp = Fs[br] + ((long)(bb * 80 + p * 8 + tt)) * 64 + s * 8;
        float4 v0 = *(const float4*)srcp;
        float4 v1 = *(const float4*)(srcp + 4);
        *(float4*)(ls + (long)g * 8) = v0;
        *(float4*)(ls + (long)g * 8 + 4) = v1;
    }
    __syncthreads();
    if (tid < 192) {
        int pair = tid >> 3, part = tid & 7;
        int br = pair >> 3, cl = pair & 7;
        float s1 = 0.f, s2 = 0.f;
        for (int b2 = 0; b2 < 16; ++b2) {
            int bb = part * 16 + b2;
            const float* base = ls + ((br * 128 + bb) * 8) * 8 + cl;
#pragma unroll
            for (int tt = 0; tt < 8; ++tt) { float v = base[tt * 8]; s1 += v; s2 += v * v; }
        }
        psum[tid] = s1; psum2[tid] = s2;
    }
    __syncthreads();
    if (tid < 24) {
        float s1 = 0.f, s2 = 0.f;
#pragma unroll
        for (int q = 0; q < 8; ++q) { s1 += psum[tid * 8 + q]; s2 += psum2[tid * 8 + q]; }
        int br = tid >> 3, cl = tid & 7, c = s * 8 + cl;
        const float* G  = br == 0 ? g1  : (br == 1 ? g2  : g3);
        const float* BE = br == 0 ? be1 : (br == 1 ? be2 : be3);
        float m  = s1 * (1.f / 1024.f);
        float var = s2 * (1.f / 1024.f) - m * m;
        float Aa = G[c] * rsqrtf(var + 1e-5f);
        coefA[tid] = Aa;
        coefB[tid] = BE[c] - Aa * m;
    }
    __syncthreads();
    const int u = tid >> 1, h0 = (tid & 1) * 96;
    const long obase = ((long)(p * 8 + s) * 128 + u) * 192 + h0;
    const int cl = u >> 4;
    const int ub = (u & 15) * 8;
    union { u16 u[8]; uint4 v; } pk;
    for (int hq = 0; hq < 12; ++hq) {
#pragma unroll
        for (int z = 0; z < 8; ++z) {
            int h = h0 + hq * 8 + z;
            int bb = ub + h / 24, t = h % 24, br = t >> 3, tt = t & 7;
            float v = ls[((br * 128 + bb) * 8 + tt) * 8 + cl];
            float r = fmaxf(v * coefA[br * 8 + cl] + coefB[br * 8 + cl], 0.f);
            pk.u[z] = f2bf(r);
        }
        *(uint4*)(xin + obase + hq * 8) = pk.v;
    }
}

// ---------------- persistent LSTM + fused Wf1: Whh lives in REGISTERS ----------------
#define LSTM_LDS (6400 + 49152)
__global__ void __launch_bounds__(512, 1)
lstm_persist(const float* __restrict__ Xg, const u16* __restrict__ Whh,
             const float* __restrict__ h0, const float* __restrict__ c0,
             const u16* __restrict__ Wf1, const float* __restrict__ bf1,
             float* __restrict__ fc1o)
{
    extern __shared__ __align__(16) u16 smem[];
    u16*   hS    = smem;                          // [16][200]
    float* gates = (float*)(smem + 16 * 200);     // [16][768]

    const int tid = threadIdx.x, wv = tid >> 6, lane = tid & 63;
    const int R0 = blockIdx.x * 16;
    const int fr = lane & 15, hi = lane >> 4;

    v8bf Wreg[6][6];
#pragma unroll
    for (int nt = 0; nt < 6; ++nt)
#pragma unroll
        for (int ks = 0; ks < 6; ++ks)
            Wreg[nt][ks] = *(const v8bf*)(Whh + (long)(nt * 128 + wv * 16 + fr) * 192 + ks * 32 + hi * 8);

    for (int i = tid; i < 16 * 200; i += 512) {
        int r = i / 200, cx = i % 200;
        hS[i] = (cx < 192) ? f2bf(h0[(R0 + r) * 192 + cx]) : (u16)0;
    }
    float creg[6];
#pragma unroll
    for (int j = 0; j < 6; ++j) {
        int e = j * 512 + tid;
        creg[j] = c0[(R0 + e / 192) * 192 + e % 192];
    }

    v4f f1acc[2] = {};
    const int nb0 = wv * 32;
    auto WF1ACC = [&](int ss, const v8bf* a) {
#pragma unroll
        for (int jf = 0; jf < 2; ++jf) {
            v4f tacc = f1acc[jf];
#pragma unroll
            for (int ks = 0; ks < 6; ++ks) {
                v8bf bfr = *(const v8bf*)(Wf1 + (long)(nb0 + jf * 16 + fr) * 1536 + ss * 192 + ks * 32 + hi * 8);
                tacc = __builtin_amdgcn_mfma_f32_16x16x32_bf16(a[ks], bfr, tacc, 0, 0, 0);
            }
            f1acc[jf] = tacc;
        }
    };

    for (int s = 0; s < 8; ++s) {
        __syncthreads();
        v8bf a[6];
#pragma unroll
        for (int ks = 0; ks < 6; ++ks)
            a[ks] = *(const v8bf*)(&hS[fr * 200 + ks * 32 + hi * 8]);
        if (s > 0) WF1ACC(s - 1, a);
#pragma unroll
        for (int nt = 0; nt < 6; ++nt) {
            v4f acc = {};
#pragma unroll
            for (int ks = 0; ks < 6; ++ks)
                acc = __builtin_amdgcn_mfma_f32_16x16x32_bf16(a[ks], Wreg[nt][ks], acc, 0, 0, 0);
            int n = nt * 128 + wv * 16 + fr;
#pragma unroll
            for (int q = 0; q < 4; ++q)
                gates[(hi * 4 + q) * 768 + n] = acc[q];
        }
        __syncthreads();
#pragma unroll
        for (int j = 0; j < 6; ++j) {
            int e = j * 512 + tid;
            int r = e / 192, hd = e % 192;
            int grow = R0 + r;
            int p = grow >> 7, u = grow & 127;
            long xrow = (long)((p * 8 + s) * 128 + u) * 768;
            float gi = Xg[xrow + hd]       + gates[r * 768 + hd];
            float gf = Xg[xrow + 192 + hd] + gates[r * 768 + 192 + hd];
            float gg = Xg[xrow + 384 + hd] + gates[r * 768 + 384 + hd];
            float go = Xg[xrow + 576 + hd] + gates[r * 768 + 576 + hd];
            float c = sigf(gf) * creg[j] + sigf(gi) * tanhf(gg);
            float h = sigf(go) * tanhf(c);
            creg[j] = c;
            hS[r * 200 + hd] = f2bf(h);
        }
    }
    __syncthreads();
    {
        v8bf a[6];
#pragma unroll
        for (int ks = 0; ks < 6; ++ks)
            a[ks] = *(const v8bf*)(&hS[fr * 200 + ks * 32 + hi * 8]);
        WF1ACC(7, a);
    }
#pragma unroll
    for (int jf = 0; jf < 2; ++jf)
#pragma unroll
        for (int q = 0; q < 4; ++q) {
            int row = hi * 4 + q;
            int n = nb0 + jf * 16 + fr;
            fc1o[(long)(R0 + row) * 256 + n] = fmaxf(f1acc[jf][q] + bf1[n], 0.f);
        }
}

// ---------------- final FC: one wave per (u, n), shuffle reduce ----------------
__global__ void __launch_bounds__(256) final_fc2(
    const float* __restrict__ fc1, const float* __restrict__ oi, const float* __restrict__ mi,
    const float* __restrict__ Wf2, const float* __restrict__ bf2, float* __restrict__ out)
{
    const int wv = threadIdx.x >> 6, lane = threadIdx.x & 63;
    const int w = blockIdx.x * 4 + wv;      // 0..1023
    const int u = w >> 3, n = w & 7;
    const float* wrow = Wf2 + n * 270;
    float wreg[4];
#pragma unroll
    for (int q = 0; q < 4; ++q) wreg[q] = wrow[lane + 64 * q];
    float wtail = (lane < 14) ? wrow[256 + lane] : 0.f;
    float acc = 0.f;
    for (int p = 0; p < 10; ++p) {
        const float* x = fc1 + (long)(p * 128 + u) * 256;
#pragma unroll
        for (int q = 0; q < 4; ++q) acc += x[lane + 64 * q] * wreg[q];
        float t = 0.f;
        if (lane < 7)       t = oi[(u * 10 + p) * 7 + lane];
        else if (lane < 14) t = mi[(u * 10 + p) * 7 + lane - 7];
        acc += t * wtail;
    }
#pragma unroll
    for (int off = 32; off; off >>= 1) acc += __shfl_xor(acc, off);
    if (lane == 0) out[u * 8 + n] = acc + bf2[n];
}

// ---------------- launcher ----------------
extern "C" void kernel_launch(void* const* d_in, const int* in_sizes, int n_in,
                              void* d_out, int out_size, void* d_ws, size_t ws_size,
                              hipStream_t stream)
{
    (void)in_sizes; (void)n_in; (void)out_size; (void)ws_size;
    const float* board = (const float*)d_in[0];
    const float* order = (const float*)d_in[1];
    const float* mess  = (const float*)d_in[2];
    const float* oi    = (const float*)d_in[3];
    const float* mi    = (const float*)d_in[4];
    const float* h0    = (const float*)d_in[5];
    const float* c0    = (const float*)d_in[6];
    const float* Wb1 = (const float*)d_in[7];  const float* bb1 = (const float*)d_in[8];
    const float* Wb2 = (const float*)d_in[9];  const float* bb2 = (const float*)d_in[10];
    const float* Wb3 = (const float*)d_in[11]; const float* bb3 = (const float*)d_in[12];
    const float* Wo1 = (const float*)d_in[13]; const float* bo1 = (const float*)d_in[14];
    const float* Wo2 = (const float*)d_in[15]; const float* bo2 = (const float*)d_in[16];
    const float* Wo3 = (const float*)d_in[17]; const float* bo3 = (const float*)d_in[18];
    const float* Wm1 = (const float*)d_in[19]; const float* bm1 = (const float*)d_in[20];
    const float* Wm2 = (const float*)d_in[21]; const float* bm2 = (const float*)d_in[22];
    const float* Wm3 = (const float*)d_in[23]; const float* bm3 = (const float*)d_in[24];
    const float* g1  = (const float*)d_in[25]; const float* be1 = (const float*)d_in[26];
    const float* g2  = (const float*)d_in[27]; const float* be2 = (const float*)d_in[28];
    const float* g3  = (const float*)d_in[29]; const float* be3 = (const float*)d_in[30];
    const float* Wih = (const float*)d_in[31]; const float* Whh = (const float*)d_in[32];
    const float* bih = (const float*)d_in[33]; const float* bhh = (const float*)d_in[34];
    const float* Wf1 = (const float*)d_in[35]; const float* bf1 = (const float*)d_in[36];
    const float* Wf2 = (const float*)d_in[37]; const float* bf2 = (const float*)d_in[38];

    uint8_t* ws = (uint8_t*)d_ws;
    u16*   xin_bf  = (u16*)(ws + OFF_XINBF);
    float* Xg      = (float*)(ws + OFF_XG);
    float* fc1o    = (float*)(ws + OFF_FC1);
    u16*   Wb1_bf  = (u16*)(ws + OFF_WB1);
    u16*   C1_bf   = (u16*)(ws + OFF_C1);
    u16*   Wb2_bf  = (u16*)(ws + OFF_WB2);
    u16*   Wb3_bf  = (u16*)(ws + OFF_WB3);
    float* bfe     = (float*)(ws + OFF_BFE);
    float* ofe     = (float*)(ws + OFF_OFE);
    float* mfe     = (float*)(ws + OFF_MFE);
    u16*   Wih_bf  = (u16*)(ws + OFF_WIH);
    u16*   Whh_bf  = (u16*)(ws + OFF_WHH);
    u16*   Wf1_bf  = (u16*)(ws + OFF_WF1);
    float* bsum    = (float*)(ws + OFF_BSUM);

    // 0) weight conversions (board conversion is fused into gemm160f)
    conv_weights<<<2048, 256, 0, stream>>>(Wb1, Wb2, Wb3, Wih, Whh, Wf1, bih, bhh,
                                           Wb1_bf, Wb2_bf, Wb3_bf, Wih_bf, Whh_bf, Wf1_bf, bsum);

    // 1) board MLP: L1 with fused f32->bf16 A staging, then L2+L3 fused
    hipFuncSetAttribute(reinterpret_cast<const void*>(gemm160f),
                        hipFuncAttributeMaxDynamicSharedMemorySize, G160_LDS);
    gemm160f<<<512, 256, G160_LDS, stream>>>(board, Wb1_bf, bb1, C1_bf, 6144);
    hipFuncSetAttribute(reinterpret_cast<const void*>(gemm_l23),
                        hipFuncAttributeMaxDynamicSharedMemorySize, L23_LDS);
    gemm_l23<<<80, 512, L23_LDS, stream>>>(C1_bf, Wb2_bf, bb2, Wb3_bf, bb3, bfe);

    // 2) order + message MLPs in one launch
    hipFuncSetAttribute(reinterpret_cast<const void*>(mlp3_dual),
                        hipFuncAttributeMaxDynamicSharedMemorySize, MLP_LDS);
    mlp3_dual<<<640, 256, MLP_LDS, stream>>>(order, Wo1, bo1, Wo2, bo2, Wo3, bo3, ofe,
                                             mess, Wm1, bm1, Wm2, bm2, Wm3, bm3, mfe);

    // 3) scramble + in-block BN stats into LSTM input
    hipFuncSetAttribute(reinterpret_cast<const void*>(build_xin2),
                        hipFuncAttributeMaxDynamicSharedMemorySize, BX_LDS);
    build_xin2<<<80, 256, BX_LDS, stream>>>(bfe, ofe, mfe, g1, be1, g2, be2, g3, be3, xin_bf);

    // 4) hoisted input-to-hidden GEMM: Xg = xin @ Wih^T + (bih + bhh)
    gemm_bt<0, 0, 1><<<dim3(6, 80), 256, 0, stream>>>(xin_bf, Wih_bf, bsum, Xg, 10240, 768, 192, 768);

    // 5) recurrence + fused Wf1/bias/relu (Whh in registers)
    hipFuncSetAttribute(reinterpret_cast<const void*>(lstm_persist),
                        hipFuncAttributeMaxDynamicSharedMemorySize, LSTM_LDS);
    lstm_persist<<<80, 512, LSTM_LDS, stream>>>(Xg, Whh_bf, h0, c0, Wf1_bf, bf1, fc1o);

    // 6) final
    final_fc2<<<256, 256, 0, stream>>>(fc1o, oi, mi, Wf2, bf2, (float*)d_out);
}

// Round 9
// 354.413 us; speedup vs baseline: 1.2447x; 1.2447x over previous
//
#include <hip/hip_runtime.h>
#include <stdint.h>

typedef unsigned short u16;
typedef __bf16 v8bf __attribute__((ext_vector_type(8)));
typedef float  v4f  __attribute__((ext_vector_type(4)));

__device__ __forceinline__ u16 f2bf(float f) {
    union { float f; unsigned u; } x; x.f = f;
    unsigned r = (x.u + 0x7FFFu + ((x.u >> 16) & 1u)) >> 16;
    return (u16)r;
}
__device__ __forceinline__ float sigf(float x) { return 1.f / (1.f + __expf(-x)); }
__device__ __forceinline__ void gload(const u16* src, u16* ldst) {
    __builtin_amdgcn_global_load_lds((const __attribute__((address_space(1))) void*)src,
                                     (__attribute__((address_space(3))) void*)ldst, 16, 0, 0);
}

// ---------------- workspace layout (bytes) ----------------
#define OFF_ABF    0UL            // u16 [10240][6144]  (dead after GEMM1)
#define OFF_XINBF  0UL            // u16 [10240][192]
#define OFF_XG     3932160UL      // f32 [10240][768]
#define OFF_FC1    44728320UL     // f32 [1280][256]
#define OFF_WB1    125829120UL    // u16 [1024][6144]
#define OFF_C1     138412032UL    // u16 [10240][1024]
#define OFF_WB2    159383552UL    // u16 [256][1024]
#define OFF_WB3    165150720UL    // u16 [128][256] (rows 64..127 zero)
#define OFF_BFE    165216256UL    // f32 [10240][64]
#define OFF_OFE    167837696UL    // f32 [10240][64]
#define OFF_MFE    170459136UL    // f32 [10240][64]
#define OFF_WIH    173095936UL    // u16 [768][192]
#define OFF_WHH    173390848UL    // u16 [768][192]
#define OFF_WF1    173685760UL    // u16 [256][1536]
#define OFF_BSUM   174472192UL    // f32 [768]  (bih+bhh)

// ---------------- converters ----------------
__global__ void __launch_bounds__(256) conv_board(const float* __restrict__ src, u16* __restrict__ dst)
{
    int bid = blockIdx.x;
    int row = bid / 6, chunk = bid - row * 6;
    int k0 = chunk * 1024 + threadIdx.x * 4;
    const float* s = src + (long)row * 6075 + k0;
    u16* d = dst + (long)row * 6144 + k0;
    if (k0 + 4 <= 6075) {
        float f0 = s[0], f1 = s[1], f2 = s[2], f3 = s[3];
        uint2 v;
        v.x = (unsigned)f2bf(f0) | ((unsigned)f2bf(f1) << 16);
        v.y = (unsigned)f2bf(f2) | ((unsigned)f2bf(f3) << 16);
        *(uint2*)d = v;
    } else {
#pragma unroll
        for (int z = 0; z < 4; ++z) {
            int k = k0 + z;
            d[z] = f2bf(k < 6075 ? s[z] : 0.f);
        }
    }
}

__global__ void __launch_bounds__(256) conv_weights(
    const float* __restrict__ Wb1, const float* __restrict__ Wb2, const float* __restrict__ Wb3,
    const float* __restrict__ Wih, const float* __restrict__ Whh, const float* __restrict__ Wf1,
    const float* __restrict__ bih, const float* __restrict__ bhh,
    u16* __restrict__ dWb1, u16* __restrict__ dWb2, u16* __restrict__ dWb3,
    u16* __restrict__ dWih, u16* __restrict__ dWhh, u16* __restrict__ dWf1,
    float* __restrict__ bsum)
{
    const long C0 = 6291456, C1 = 6553600, C2 = 6586368, C3 = 6733824,
               C4 = 6881280, C5 = 7274496, C6 = 7275264;
    for (long i = (long)blockIdx.x * 256 + threadIdx.x; i < C6; i += (long)gridDim.x * 256) {
        if (i < C0) {
            int r = (int)(i / 6144), k = (int)(i % 6144);
            dWb1[i] = f2bf(k < 6075 ? Wb1[(long)r * 6075 + k] : 0.f);
        } else if (i < C1) {
            long j = i - C0;
            dWb2[j] = f2bf(Wb2[j]);
        } else if (i < C2) {
            long j = i - C1;
            dWb3[j] = f2bf(j < 16384 ? Wb3[j] : 0.f);
        } else if (i < C3) {
            long j = i - C2;
            dWih[j] = f2bf(Wih[j]);
        } else if (i < C4) {
            long j = i - C3;
            dWhh[j] = f2bf(Whh[j]);
        } else if (i < C5) {
            long j = i - C4;
            dWf1[j] = f2bf(Wf1[j]);
        } else {
            long j = i - C5;
            bsum[j] = bih[j] + bhh[j];
        }
    }
}

// ---------------- L1 GEMM: BM=160 x BN=128, 256 thr (4 waves, 80x64 each) -----------
// grid 512 = 2 blocks/CU. XCD mapping: all 8 column-blocks of a row-tile on the SAME
// XCD (bid%8 = rowt%8) -> shared A-panel slice L2-resident; B re-reads are L3-hits.
#define G160_LDS 73728
__global__ void __launch_bounds__(256, 2)
gemm160(const u16* __restrict__ A, const u16* __restrict__ B,
        const float* __restrict__ bias, u16* __restrict__ C, int K)
{
    extern __shared__ __align__(16) u16 smem[];   // [2][A 160x64 | B 128x64]
    const int tid = threadIdx.x, wv = tid >> 6, lane = tid & 63;
    const int bid = blockIdx.x;
    const int k8 = bid & 7;                  // XCD id
    const int j  = bid >> 3;                 // 0..63
    const int rowt = k8 + (j >> 3) * 8;      // row-tile pinned to XCD
    const int col  = j & 7;
    const long m0 = (long)rowt * 160;
    const long n0 = (long)col * 128;

    const int sr8 = lane >> 3;
    const int sslot = (lane & 7) ^ sr8;
    const u16* Ag = A + (m0 + wv * 8 + sr8) * (long)K + sslot * 8;
    const u16* Bg = B + (n0 + wv * 8 + sr8) * (long)K + sslot * 8;
    const int wr = wv >> 1, wc = wv & 1;
    const int wm = wr * 80, wn = wc * 64;
    const int fr = lane & 15, hi = lane >> 4, fx = fr & 7;

    const int nk = K >> 6;
    v4f acc[5][4] = {};

    auto STAGE = [&](int buf, int t) {
        const long k0 = (long)t * 64;
        const int ab = buf * 18432;
#pragma unroll
        for (int r = 0; r < 5; ++r)
            gload(Ag + (long)r * 32 * K + k0, smem + ab + r * 2048 + wv * 512);
#pragma unroll
        for (int r = 0; r < 4; ++r)
            gload(Bg + (long)r * 32 * K + k0, smem + ab + 10240 + r * 2048 + wv * 512);
    };
    auto LDA_ = [&](int buf, int ks, int i) -> v8bf {
        return *(const v8bf*)(smem + buf * 18432 + (wm + i * 16 + fr) * 64 + ((ks * 4 + hi) ^ fx) * 8);
    };
    auto LDB_ = [&](int buf, int ks, int j2) -> v8bf {
        return *(const v8bf*)(smem + buf * 18432 + 10240 + (wn + j2 * 16 + fr) * 64 + ((ks * 4 + hi) ^ fx) * 8);
    };

    STAGE(0, 0);
    STAGE(1, 1);
    for (int t = 0; t < nk; ++t) {
        const int buf = t & 1;
        if (t + 1 < nk) { asm volatile("s_waitcnt vmcnt(9)" ::: "memory"); }
        else            { asm volatile("s_waitcnt vmcnt(0)" ::: "memory"); }
        asm volatile("s_barrier" ::: "memory");
        __builtin_amdgcn_s_setprio(1);
        v8bf a0[5], a1[5], b0[4], b1[4];
#pragma unroll
        for (int j2 = 0; j2 < 4; ++j2) b0[j2] = LDB_(buf, 0, j2);
#pragma unroll
        for (int i = 0; i < 5; ++i) a0[i] = LDA_(buf, 0, i);
        __builtin_amdgcn_sched_barrier(0);
#pragma unroll
        for (int j2 = 0; j2 < 4; ++j2) b1[j2] = LDB_(buf, 1, j2);
#pragma unroll
        for (int i = 0; i < 5; ++i) a1[i] = LDA_(buf, 1, i);
#pragma unroll
        for (int i = 0; i < 5; ++i)
#pragma unroll
            for (int j2 = 0; j2 < 4; ++j2)
                acc[i][j2] = __builtin_amdgcn_mfma_f32_16x16x32_bf16(a0[i], b0[j2], acc[i][j2], 0, 0, 0);
        __builtin_amdgcn_sched_barrier(0);
        __builtin_amdgcn_s_setprio(0);
        asm volatile("s_waitcnt lgkmcnt(0)" ::: "memory");
        __builtin_amdgcn_sched_barrier(0);
        asm volatile("s_barrier" ::: "memory");
        if (t + 2 < nk) STAGE(buf, t + 2);
        __builtin_amdgcn_s_setprio(1);
#pragma unroll
        for (int i = 0; i < 5; ++i)
#pragma unroll
            for (int j2 = 0; j2 < 4; ++j2)
                acc[i][j2] = __builtin_amdgcn_mfma_f32_16x16x32_bf16(a1[i], b1[j2], acc[i][j2], 0, 0, 0);
        __builtin_amdgcn_s_setprio(0);
    }

#pragma unroll
    for (int i = 0; i < 5; ++i) {
        const long mr = m0 + wm + i * 16 + hi * 4;
#pragma unroll
        for (int j2 = 0; j2 < 4; ++j2) {
            const long n = n0 + wn + j2 * 16 + fr;
            float bv = bias[n];
#pragma unroll
            for (int r = 0; r < 4; ++r) {
                float v = fmaxf(acc[i][j2][r] + bv, 0.f);
                C[(mr + r) * 1024L + n] = f2bf(v);
            }
        }
    }
}

// ---------------- L2 GEMM (BM=64 BN=256 K=1024) with fused L3 epilogue --------------
// grid 160 (62.5% fill, was 80/31%). 512 thr = 8 waves (2M x 4N), wave tile 32x64.
// LDS dbuf 80KB. Epilogue: relu(C2+b2)->bf16 LDS [64][264], waves 0-3 MFMA vs Wb3.
#define L23_LDS 81920
__global__ void __launch_bounds__(512, 1)
gemm_l23(const u16* __restrict__ A, const u16* __restrict__ B, const float* __restrict__ b2,
         const u16* __restrict__ W3, const float* __restrict__ b3, float* __restrict__ Out)
{
    extern __shared__ __align__(16) u16 smem[];   // [2][A 64x64 | B 256x64]
    const int tid = threadIdx.x, wv = tid >> 6, lane = tid & 63;
    const long m0 = (long)blockIdx.x * 64;
    const int sr8 = lane >> 3;
    const int sslot = (lane & 7) ^ sr8;
    const u16* Ag = A + (m0 + wv * 8 + sr8) * 1024L + sslot * 8;
    const u16* Bg = B + (wv * 8 + sr8) * 1024L + sslot * 8;
    const int wr = wv >> 2, wc = wv & 3;
    const int wm = wr * 32, wn = wc * 64;
    const int fr = lane & 15, hi = lane >> 4, fx = fr & 7;

    v4f acc[2][4] = {};

    auto STAGE = [&](int buf, int t) {
        const long k0 = (long)t * 64;
        const int ab = buf * 20480;
        gload(Ag + k0, smem + ab + wv * 512);                       // A: 64 rows, 1 round
#pragma unroll
        for (int r = 0; r < 4; ++r)                                  // B: 256 rows, 4 rounds
            gload(Bg + (long)r * 64 * 1024 + k0, smem + ab + 4096 + r * 4096 + wv * 512);
    };
    auto COMPUTE = [&](int buf) {
#pragma unroll
        for (int ks = 0; ks < 2; ++ks) {
            const int sw = ((ks * 4 + hi) ^ fx) * 8;
            v8bf a[2], b[4];
#pragma unroll
            for (int i = 0; i < 2; ++i)
                a[i] = *(const v8bf*)(smem + buf * 20480 + (wm + i * 16 + fr) * 64 + sw);
#pragma unroll
            for (int j = 0; j < 4; ++j)
                b[j] = *(const v8bf*)(smem + buf * 20480 + 4096 + (wn + j * 16 + fr) * 64 + sw);
#pragma unroll
            for (int i = 0; i < 2; ++i)
#pragma unroll
                for (int j = 0; j < 4; ++j)
                    acc[i][j] = __builtin_amdgcn_mfma_f32_16x16x32_bf16(a[i], b[j], acc[i][j], 0, 0, 0);
        }
    };

    STAGE(0, 0);
    __syncthreads();
    int t = 1;
    while (true) {
        if (t < 16) STAGE(1, t);
        COMPUTE(0);
        if (t >= 16) break;
        __syncthreads();
        ++t;
        if (t < 16) STAGE(0, t);
        COMPUTE(1);
        if (t >= 16) break;
        __syncthreads();
        ++t;
    }
    __syncthreads();
    // epilogue 1: relu(C2 + b2) -> bf16 into LDS [64][264]
    u16* C2s = smem;
#pragma unroll
    for (int i = 0; i < 2; ++i) {
        const int rrow = wm + i * 16 + hi * 4;
#pragma unroll
        for (int j = 0; j < 4; ++j) {
            const int ccol = wn + j * 16 + fr;
            float bv = b2[ccol];
#pragma unroll
            for (int r = 0; r < 4; ++r)
                C2s[(rrow + r) * 264 + ccol] = f2bf(fmaxf(acc[i][j][r] + bv, 0.f));
        }
    }
    __syncthreads();
    // epilogue 2: waves 0-3, 16 rows each: C3 = C2 @ Wb3^T + b3
    if (wv < 4) {
        v4f a3[4] = {};
#pragma unroll
        for (int kk = 0; kk < 8; ++kk) {
            v8bf af = *(const v8bf*)(&C2s[(wv * 16 + fr) * 264 + kk * 32 + hi * 8]);
#pragma unroll
            for (int j = 0; j < 4; ++j) {
                v8bf bfr = *(const v8bf*)(W3 + (j * 16 + fr) * 256 + kk * 32 + hi * 8);
                a3[j] = __builtin_amdgcn_mfma_f32_16x16x32_bf16(af, bfr, a3[j], 0, 0, 0);
            }
        }
#pragma unroll
        for (int j = 0; j < 4; ++j) {
            int n = j * 16 + fr;
            float bv = b3[n];
#pragma unroll
            for (int q = 0; q < 4; ++q)
                Out[(m0 + wv * 16 + hi * 4 + q) * 64 + n] = a3[j][q] + bv;
        }
    }
}

// ---------------- bf16 MFMA GEMM 128x128 (used for Xg only) ----------------
template<int OBF, int RELU, int BIAS>
__global__ void __launch_bounds__(256)
gemm_bt(const u16* __restrict__ A, const u16* __restrict__ B,
        const float* __restrict__ bias, void* __restrict__ Cv,
        int M, int N, int K, int ldc)
{
    __shared__ __align__(16) u16 As[2][128 * 64];
    __shared__ __align__(16) u16 Bs[2][128 * 64];
    const int tid = threadIdx.x;
    const int wv = tid >> 6, lane = tid & 63;
    const long m0 = (long)blockIdx.y * 128;
    const long n0 = (long)blockIdx.x * 128;
    const int srow  = wv * 8 + (lane >> 3);
    const int sslot = (lane & 7) ^ (lane >> 3);
    const u16* Ag = A + (m0 + srow) * (long)K + sslot * 8;
    const u16* Bg = B + (n0 + srow) * (long)K + sslot * 8;
    const int wm = (wv >> 1) * 64, wn = (wv & 1) * 64;
    const int fr = lane & 15, hi = lane >> 4;
    const int fx = fr & 7;

    v4f acc[4][4] = {};
    const int nk = K >> 6;

    auto STAGE = [&](int buf, int k0) {
#pragma unroll
        for (int r = 0; r < 4; ++r)
            gload(Ag + (long)r * 32 * K + k0, &As[buf][r * 2048 + wv * 512]);
#pragma unroll
        for (int r = 0; r < 4; ++r)
            gload(Bg + (long)r * 32 * K + k0, &Bs[buf][r * 2048 + wv * 512]);
    };
    auto COMPUTE = [&](int buf) {
#pragma unroll
        for (int ks = 0; ks < 2; ++ks) {
            v8bf a[4], b[4];
            const int sw = (((ks * 4 + hi) ^ fx)) * 8;
#pragma unroll
            for (int i = 0; i < 4; ++i)
                a[i] = *(const v8bf*)(&As[buf][(wm + i * 16 + fr) * 64 + sw]);
#pragma unroll
            for (int j = 0; j < 4; ++j)
                b[j] = *(const v8bf*)(&Bs[buf][(wn + j * 16 + fr) * 64 + sw]);
#pragma unroll
            for (int i = 0; i < 4; ++i)
#pragma unroll
                for (int j = 0; j < 4; ++j)
                    acc[i][j] = __builtin_amdgcn_mfma_f32_16x16x32_bf16(a[i], b[j], acc[i][j], 0, 0, 0);
        }
    };

    STAGE(0, 0);
    __syncthreads();
    int t = 1;
    while (true) {
        if (t < nk) STAGE(1, t * 64);
        COMPUTE(0);
        if (t >= nk) break;
        __syncthreads();
        ++t;
        if (t < nk) STAGE(0, t * 64);
        COMPUTE(1);
        if (t >= nk) break;
        __syncthreads();
        ++t;
    }

#pragma unroll
    for (int i = 0; i < 4; ++i) {
        const long mr = m0 + wm + i * 16 + hi * 4;
#pragma unroll
        for (int j = 0; j < 4; ++j) {
            const long n = n0 + wn + j * 16 + fr;
            if (n < N) {
                float bv = BIAS ? bias[n] : 0.f;
#pragma unroll
                for (int r = 0; r < 4; ++r) {
                    float v = acc[i][j][r] + bv;
                    if (RELU) v = fmaxf(v, 0.f);
                    if (OBF) ((u16*)Cv)[(mr + r) * (long)ldc + n] = f2bf(v);
                    else     ((float*)Cv)[(mr + r) * (long)ldc + n] = v;
                }
            }
        }
    }
}

// ---------------- small 3-layer MLP body (order/message), f32, LDS-resident ----------
template<int D0, int D1>
__device__ __forceinline__ void mlp3_body(
    float* sm, const float* __restrict__ X,
    const float* __restrict__ W1, const float* __restrict__ B1,
    const float* __restrict__ W2, const float* __restrict__ B2,
    const float* __restrict__ W3, const float* __restrict__ B3,
    float* __restrict__ Out, int blk)
{
    float* w1s = sm;
    float* w2s = w1s + D0 * D1;
    float* w3s = w2s + D1 * 32;
    float* b1s = w3s + 32 * 64;
    float* b2s = b1s + D1;
    float* b3s = b2s + 32;
    float* xs  = b3s + 64;
    float* h1  = xs + 32 * D0;
    float* h2  = h1 + 32 * D1;

    const int tid = threadIdx.x;
    const long row0 = (long)blk * 32;

    for (int i = tid; i < D0 * D1; i += 256) { int k = i / D1, n = i % D1; w1s[i] = W1[n * D0 + k]; }
    for (int i = tid; i < D1 * 32; i += 256) { int k = i / 32,  n = i % 32; w2s[i] = W2[n * D1 + k]; }
    for (int i = tid; i < 32 * 64; i += 256) { int k = i / 64,  n = i % 64; w3s[i] = W3[n * 32 + k]; }
    if (tid < D1) b1s[tid] = B1[tid];
    if (tid < 32) b2s[tid] = B2[tid];
    if (tid < 64) b3s[tid] = B3[tid];
    for (int i = tid; i < 32 * D0; i += 256) xs[i] = X[(row0 + i / D0) * D0 + i % D0];
    __syncthreads();

    const int wv = tid >> 6, lane = tid & 63;
    const int r0 = wv * 8;
    {
        constexpr int NL = D1 / 64;
        float acc[NL][8];
#pragma unroll
        for (int a = 0; a < NL; ++a)
#pragma unroll
            for (int r = 0; r < 8; ++r) acc[a][r] = 0.f;
        for (int k = 0; k < D0; ++k) {
            float w[NL];
#pragma unroll
            for (int a = 0; a < NL; ++a) w[a] = w1s[k * D1 + lane + a * 64];
#pragma unroll
            for (int r = 0; r < 8; ++r) {
                float x = xs[(r0 + r) * D0 + k];
#pragma unroll
                for (int a = 0; a < NL; ++a) acc[a][r] += w[a] * x;
            }
        }
#pragma unroll
        for (int a = 0; a < NL; ++a)
#pragma unroll
            for (int r = 0; r < 8; ++r)
                h1[(r0 + r) * D1 + lane + a * 64] = fmaxf(acc[a][r] + b1s[lane + a * 64], 0.f);
    }
    __syncthreads();
    {
        int n = lane & 31;
        int rb = r0 + (lane >> 5) * 4;
        float acc[4] = {0, 0, 0, 0};
        for (int k = 0; k < D1; ++k) {
            float w = w2s[k * 32 + n];
#pragma unroll
            for (int r = 0; r < 4; ++r) acc[r] += w * h1[(rb + r) * D1 + k];
        }
#pragma unroll
        for (int r = 0; r < 4; ++r) h2[(rb + r) * 32 + n] = fmaxf(acc[r] + b2s[n], 0.f);
    }
    __syncthreads();
    {
        float acc[8] = {};
        for (int k = 0; k < 32; ++k) {
            float w = w3s[k * 64 + lane];
#pragma unroll
            for (int r = 0; r < 8; ++r) acc[r] += w * h2[(r0 + r) * 32 + k];
        }
#pragma unroll
        for (int r = 0; r < 8; ++r) Out[(row0 + r0 + r) * 64 + lane] = acc[r] + b3s[lane];
    }
}

#define MLP_LDS 71552
__global__ void __launch_bounds__(256)
mlp3_dual(const float* __restrict__ Xo,
          const float* __restrict__ Wo1, const float* __restrict__ bo1,
          const float* __restrict__ Wo2, const float* __restrict__ bo2,
          const float* __restrict__ Wo3, const float* __restrict__ bo3,
          float* __restrict__ ofe,
          const float* __restrict__ Xm,
          const float* __restrict__ Wm1, const float* __restrict__ bm1,
          const float* __restrict__ Wm2, const float* __restrict__ bm2,
          const float* __restrict__ Wm3, const float* __restrict__ bm3,
          float* __restrict__ mfe)
{
    extern __shared__ __align__(16) float sm[];
    if (blockIdx.x < 320)
        mlp3_body<40, 128>(sm, Xo, Wo1, bo1, Wo2, bo2, Wo3, bo3, ofe, blockIdx.x);
    else
        mlp3_body<20, 64>(sm, Xm, Wm1, bm1, Wm2, bm2, Wm3, bm3, mfe, blockIdx.x - 320);
}

// ---------------- scramble + in-block BN stats + relu -> LSTM input (bf16) ------------
#define BX_LDS 100032
__global__ void __launch_bounds__(256, 1)
build_xin2(const float* __restrict__ bfe, const float* __restrict__ ofe, const float* __restrict__ mfe,
           const float* __restrict__ g1, const float* __restrict__ be1,
           const float* __restrict__ g2, const float* __restrict__ be2,
           const float* __restrict__ g3, const float* __restrict__ be3,
           u16* __restrict__ xin)
{
    extern __shared__ __align__(16) float ls[];   // [3][128][8][8]
    float* coefA = ls + 24576;
    float* coefB = coefA + 24;
    float* psum  = coefB + 24;
    float* psum2 = psum + 192;
    const int p = blockIdx.x >> 3, s = blockIdx.x & 7;
    const int tid = threadIdx.x;
    const float* Fs[3] = {bfe, ofe, mfe};
    for (int g = tid; g < 3072; g += 256) {
        int br = g >> 10, rr = g & 1023, bb = rr >> 3, tt = rr & 7;
        const float* srcp = Fs[br] + ((long)(bb * 80 + p * 8 + tt)) * 64 + s * 8;
        float4 v0 = *(const float4*)srcp;
        float4 v1 = *(const float4*)(srcp + 4);
        *(float4*)(ls + (long)g * 8) = v0;
        *(float4*)(ls + (long)g * 8 + 4) = v1;
    }
    __syncthreads();
    if (tid < 192) {
        int pair = tid >> 3, part = tid & 7;
        int br = pair >> 3, cl = pair & 7;
        float s1 = 0.f, s2 = 0.f;
        for (int b2 = 0; b2 < 16; ++b2) {
            int bb = part * 16 + b2;
            const float* base = ls + ((br * 128 + bb) * 8) * 8 + cl;
#pragma unroll
            for (int tt = 0; tt < 8; ++tt) { float v = base[tt * 8]; s1 += v; s2 += v * v; }
        }
        psum[tid] = s1; psum2[tid] = s2;
    }
    __syncthreads();
    if (tid < 24) {
        float s1 = 0.f, s2 = 0.f;
#pragma unroll
        for (int q = 0; q < 8; ++q) { s1 += psum[tid * 8 + q]; s2 += psum2[tid * 8 + q]; }
        int br = tid >> 3, cl = tid & 7, c = s * 8 + cl;
        const float* G  = br == 0 ? g1  : (br == 1 ? g2  : g3);
        const float* BE = br == 0 ? be1 : (br == 1 ? be2 : be3);
        float m  = s1 * (1.f / 1024.f);
        float var = s2 * (1.f / 1024.f) - m * m;
        float Aa = G[c] * rsqrtf(var + 1e-5f);
        coefA[tid] = Aa;
        coefB[tid] = BE[c] - Aa * m;
    }
    __syncthreads();
    const int u = tid >> 1, h0 = (tid & 1) * 96;
    const long obase = ((long)(p * 8 + s) * 128 + u) * 192 + h0;
    const int cl = u >> 4;
    const int ub = (u & 15) * 8;
    union { u16 u[8]; uint4 v; } pk;
    for (int hq = 0; hq < 12; ++hq) {
#pragma unroll
        for (int z = 0; z < 8; ++z) {
            int h = h0 + hq * 8 + z;
            int bb = ub + h / 24, t = h % 24, br = t >> 3, tt = t & 7;
            float v = ls[((br * 128 + bb) * 8 + tt) * 8 + cl];
            float r = fmaxf(v * coefA[br * 8 + cl] + coefB[br * 8 + cl], 0.f);
            pk.u[z] = f2bf(r);
        }
        *(uint4*)(xin + obase + hq * 8) = pk.v;
    }
}

// ---------------- persistent LSTM + fused Wf1: 160 blocks x 8 rows --------------------
// Whh register tile is block-replicated (same 144 VGPR/thread regardless of rows), so
// halving rows/block doubles CU fill for free. hS rows 8-15 zeroed; MFMA output rows
// 8-15 discarded (output row r depends only on A row r -> garbage rows are inert).
#define LSTM_LDS (6400 + 24576)
__global__ void __launch_bounds__(512, 1)
lstm_persist(const float* __restrict__ Xg, const u16* __restrict__ Whh,
             const float* __restrict__ h0, const float* __restrict__ c0,
             const u16* __restrict__ Wf1, const float* __restrict__ bf1,
             float* __restrict__ fc1o)
{
    extern __shared__ __align__(16) u16 smem[];
    u16*   hS    = smem;                          // [16][200] (rows 8-15 zero)
    float* gates = (float*)(smem + 16 * 200);     // [8][768]

    const int tid = threadIdx.x, wv = tid >> 6, lane = tid & 63;
    const int R0 = blockIdx.x * 8;
    const int fr = lane & 15, hi = lane >> 4;

    v8bf Wreg[6][6];
#pragma unroll
    for (int nt = 0; nt < 6; ++nt)
#pragma unroll
        for (int ks = 0; ks < 6; ++ks)
            Wreg[nt][ks] = *(const v8bf*)(Whh + (long)(nt * 128 + wv * 16 + fr) * 192 + ks * 32 + hi * 8);

    for (int i = tid; i < 16 * 200; i += 512) {
        int r = i / 200, cx = i % 200;
        u16 v = 0;
        if (r < 8 && cx < 192) v = f2bf(h0[(R0 + r) * 192 + cx]);
        hS[i] = v;
    }
    float creg[3];
#pragma unroll
    for (int j = 0; j < 3; ++j) {
        int e = j * 512 + tid;
        creg[j] = c0[(R0 + e / 192) * 192 + e % 192];
    }

    v4f f1acc[2] = {};
    const int nb0 = wv * 32;
    auto WF1ACC = [&](int ss, const v8bf* a) {
#pragma unroll
        for (int jf = 0; jf < 2; ++jf) {
            v4f tacc = f1acc[jf];
#pragma unroll
            for (int ks = 0; ks < 6; ++ks) {
                v8bf bfr = *(const v8bf*)(Wf1 + (long)(nb0 + jf * 16 + fr) * 1536 + ss * 192 + ks * 32 + hi * 8);
                tacc = __builtin_amdgcn_mfma_f32_16x16x32_bf16(a[ks], bfr, tacc, 0, 0, 0);
            }
            f1acc[jf] = tacc;
        }
    };

    for (int s = 0; s < 8; ++s) {
        __syncthreads();
        v8bf a[6];
#pragma unroll
        for (int ks = 0; ks < 6; ++ks)
            a[ks] = *(const v8bf*)(&hS[fr * 200 + ks * 32 + hi * 8]);
        if (s > 0) WF1ACC(s - 1, a);
#pragma unroll
        for (int nt = 0; nt < 6; ++nt) {
            v4f acc = {};
#pragma unroll
            for (int ks = 0; ks < 6; ++ks)
                acc = __builtin_amdgcn_mfma_f32_16x16x32_bf16(a[ks], Wreg[nt][ks], acc, 0, 0, 0);
            int n = nt * 128 + wv * 16 + fr;
            if (hi < 2) {                         // output rows 0-7 only
#pragma unroll
                for (int q = 0; q < 4; ++q)
                    gates[(hi * 4 + q) * 768 + n] = acc[q];
            }
        }
        __syncthreads();
#pragma unroll
        for (int j = 0; j < 3; ++j) {
            int e = j * 512 + tid;
            int r = e / 192, hd = e % 192;
            int grow = R0 + r;
            int p = grow >> 7, u = grow & 127;
            long xrow = (long)((p * 8 + s) * 128 + u) * 768;
            float gi = Xg[xrow + hd]       + gates[r * 768 + hd];
            float gf = Xg[xrow + 192 + hd] + gates[r * 768 + 192 + hd];
            float gg = Xg[xrow + 384 + hd] + gates[r * 768 + 384 + hd];
            float go = Xg[xrow + 576 + hd] + gates[r * 768 + 576 + hd];
            float c = sigf(gf) * creg[j] + sigf(gi) * tanhf(gg);
            float h = sigf(go) * tanhf(c);
            creg[j] = c;
            hS[r * 200 + hd] = f2bf(h);
        }
    }
    __syncthreads();
    {
        v8bf a[6];
#pragma unroll
        for (int ks = 0; ks < 6; ++ks)
            a[ks] = *(const v8bf*)(&hS[fr * 200 + ks * 32 + hi * 8]);
        WF1ACC(7, a);
    }
    if (hi < 2) {
#pragma unroll
        for (int jf = 0; jf < 2; ++jf)
#pragma unroll
            for (int q = 0; q < 4; ++q) {
                int row = hi * 4 + q;
                int n = nb0 + jf * 16 + fr;
                fc1o[(long)(R0 + row) * 256 + n] = fmaxf(f1acc[jf][q] + bf1[n], 0.f);
            }
    }
}

// ---------------- final FC: one wave per (u, n), shuffle reduce ----------------
__global__ void __launch_bounds__(256) final_fc2(
    const float* __restrict__ fc1, const float* __restrict__ oi, const float* __restrict__ mi,
    const float* __restrict__ Wf2, const float* __restrict__ bf2, float* __restrict__ out)
{
    const int wv = threadIdx.x >> 6, lane = threadIdx.x & 63;
    const int w = blockIdx.x * 4 + wv;      // 0..1023
    const int u = w >> 3, n = w & 7;
    const float* wrow = Wf2 + n * 270;
    float wreg[4];
#pragma unroll
    for (int q = 0; q < 4; ++q) wreg[q] = wrow[lane + 64 * q];
    float wtail = (lane < 14) ? wrow[256 + lane] : 0.f;
    float acc = 0.f;
    for (int p = 0; p < 10; ++p) {
        const float* x = fc1 + (long)(p * 128 + u) * 256;
#pragma unroll
        for (int q = 0; q < 4; ++q) acc += x[lane + 64 * q] * wreg[q];
        float t = 0.f;
        if (lane < 7)       t = oi[(u * 10 + p) * 7 + lane];
        else if (lane < 14) t = mi[(u * 10 + p) * 7 + lane - 7];
        acc += t * wtail;
    }
#pragma unroll
    for (int off = 32; off; off >>= 1) acc += __shfl_xor(acc, off);
    if (lane == 0) out[u * 8 + n] = acc + bf2[n];
}

// ---------------- launcher ----------------
extern "C" void kernel_launch(void* const* d_in, const int* in_sizes, int n_in,
                              void* d_out, int out_size, void* d_ws, size_t ws_size,
                              hipStream_t stream)
{
    (void)in_sizes; (void)n_in; (void)out_size; (void)ws_size;
    const float* board = (const float*)d_in[0];
    const float* order = (const float*)d_in[1];
    const float* mess  = (const float*)d_in[2];
    const float* oi    = (const float*)d_in[3];
    const float* mi    = (const float*)d_in[4];
    const float* h0    = (const float*)d_in[5];
    const float* c0    = (const float*)d_in[6];
    const float* Wb1 = (const float*)d_in[7];  const float* bb1 = (const float*)d_in[8];
    const float* Wb2 = (const float*)d_in[9];  const float* bb2 = (const float*)d_in[10];
    const float* Wb3 = (const float*)d_in[11]; const float* bb3 = (const float*)d_in[12];
    const float* Wo1 = (const float*)d_in[13]; const float* bo1 = (const float*)d_in[14];
    const float* Wo2 = (const float*)d_in[15]; const float* bo2 = (const float*)d_in[16];
    const float* Wo3 = (const float*)d_in[17]; const float* bo3 = (const float*)d_in[18];
    const float* Wm1 = (const float*)d_in[19]; const float* bm1 = (const float*)d_in[20];
    const float* Wm2 = (const float*)d_in[21]; const float* bm2 = (const float*)d_in[22];
    const float* Wm3 = (const float*)d_in[23]; const float* bm3 = (const float*)d_in[24];
    const float* g1  = (const float*)d_in[25]; const float* be1 = (const float*)d_in[26];
    const float* g2  = (const float*)d_in[27]; const float* be2 = (const float*)d_in[28];
    const float* g3  = (const float*)d_in[29]; const float* be3 = (const float*)d_in[30];
    const float* Wih = (const float*)d_in[31]; const float* Whh = (const float*)d_in[32];
    const float* bih = (const float*)d_in[33]; const float* bhh = (const float*)d_in[34];
    const float* Wf1 = (const float*)d_in[35]; const float* bf1 = (const float*)d_in[36];
    const float* Wf2 = (const float*)d_in[37]; const float* bf2 = (const float*)d_in[38];

    uint8_t* ws = (uint8_t*)d_ws;
    u16*   A_bf    = (u16*)(ws + OFF_ABF);
    u16*   xin_bf  = (u16*)(ws + OFF_XINBF);
    float* Xg      = (float*)(ws + OFF_XG);
    float* fc1o    = (float*)(ws + OFF_FC1);
    u16*   Wb1_bf  = (u16*)(ws + OFF_WB1);
    u16*   C1_bf   = (u16*)(ws + OFF_C1);
    u16*   Wb2_bf  = (u16*)(ws + OFF_WB2);
    u16*   Wb3_bf  = (u16*)(ws + OFF_WB3);
    float* bfe     = (float*)(ws + OFF_BFE);
    float* ofe     = (float*)(ws + OFF_OFE);
    float* mfe     = (float*)(ws + OFF_MFE);
    u16*   Wih_bf  = (u16*)(ws + OFF_WIH);
    u16*   Whh_bf  = (u16*)(ws + OFF_WHH);
    u16*   Wf1_bf  = (u16*)(ws + OFF_WF1);
    float* bsum    = (float*)(ws + OFF_BSUM);

    // 0) conversions
    conv_board<<<61440, 256, 0, stream>>>(board, A_bf);
    conv_weights<<<2048, 256, 0, stream>>>(Wb1, Wb2, Wb3, Wih, Whh, Wf1, bih, bhh,
                                           Wb1_bf, Wb2_bf, Wb3_bf, Wih_bf, Whh_bf, Wf1_bf, bsum);

    // 1) board MLP: L1 (512-block, 2/CU, XCD-row mapping), then L2+L3 fused (160 blocks)
    hipFuncSetAttribute(reinterpret_cast<const void*>(gemm160),
                        hipFuncAttributeMaxDynamicSharedMemorySize, G160_LDS);
    gemm160<<<512, 256, G160_LDS, stream>>>(A_bf, Wb1_bf, bb1, C1_bf, 6144);
    hipFuncSetAttribute(reinterpret_cast<const void*>(gemm_l23),
                        hipFuncAttributeMaxDynamicSharedMemorySize, L23_LDS);
    gemm_l23<<<160, 512, L23_LDS, stream>>>(C1_bf, Wb2_bf, bb2, Wb3_bf, bb3, bfe);

    // 2) order + message MLPs in one launch
    hipFuncSetAttribute(reinterpret_cast<const void*>(mlp3_dual),
                        hipFuncAttributeMaxDynamicSharedMemorySize, MLP_LDS);
    mlp3_dual<<<640, 256, MLP_LDS, stream>>>(order, Wo1, bo1, Wo2, bo2, Wo3, bo3, ofe,
                                             mess, Wm1, bm1, Wm2, bm2, Wm3, bm3, mfe);

    // 3) scramble + in-block BN stats into LSTM input
    hipFuncSetAttribute(reinterpret_cast<const void*>(build_xin2),
                        hipFuncAttributeMaxDynamicSharedMemorySize, BX_LDS);
    build_xin2<<<80, 256, BX_LDS, stream>>>(bfe, ofe, mfe, g1, be1, g2, be2, g3, be3, xin_bf);

    // 4) hoisted input-to-hidden GEMM: Xg = xin @ Wih^T + (bih + bhh)
    gemm_bt<0, 0, 1><<<dim3(6, 80), 256, 0, stream>>>(xin_bf, Wih_bf, bsum, Xg, 10240, 768, 192, 768);

    // 5) recurrence + fused Wf1/bias/relu (Whh in registers, 160 blocks x 8 rows)
    hipFuncSetAttribute(reinterpret_cast<const void*>(lstm_persist),
                        hipFuncAttributeMaxDynamicSharedMemorySize, LSTM_LDS);
    lstm_persist<<<160, 512, LSTM_LDS, stream>>>(Xg, Whh_bf, h0, c0, Wf1_bf, bf1, fc1o);

    // 6) final
    final_fc2<<<256, 256, 0, stream>>>(fc1o, oi, mi, Wf2, bf2, (float*)d_out);
}

// Round 10
// 347.900 us; speedup vs baseline: 1.2680x; 1.0187x over previous
//
#include <hip/hip_runtime.h>
#include <stdint.h>

typedef unsigned short u16;
typedef __bf16 v8bf __attribute__((ext_vector_type(8)));
typedef float  v4f  __attribute__((ext_vector_type(4)));

__device__ __forceinline__ u16 f2bf(float f) {
    union { float f; unsigned u; } x; x.f = f;
    unsigned r = (x.u + 0x7FFFu + ((x.u >> 16) & 1u)) >> 16;
    return (u16)r;
}
__device__ __forceinline__ float sigf(float x) { return 1.f / (1.f + __expf(-x)); }
__device__ __forceinline__ void gload(const u16* src, u16* ldst) {
    __builtin_amdgcn_global_load_lds((const __attribute__((address_space(1))) void*)src,
                                     (__attribute__((address_space(3))) void*)ldst, 16, 0, 0);
}

// ---------------- workspace layout (bytes) ----------------
#define OFF_ABF    0UL            // u16 [10240][6144]  (dead after GEMM1)
#define OFF_XG     3932160UL      // f32 [10240][768]   (written after GEMM1)
#define OFF_FC1    44728320UL     // f32 [1280][256]
#define OFF_WB1    125829120UL    // u16 [1024][6144]
#define OFF_C1     138412032UL    // u16 [10240][1024]
#define OFF_WB2    159383552UL    // u16 [256][1024]
#define OFF_WB3    165150720UL    // u16 [128][256] (rows 64..127 zero)
#define OFF_BFE    165216256UL    // f32 [10240][64]
#define OFF_OFE    167837696UL    // f32 [10240][64]
#define OFF_MFE    170459136UL    // f32 [10240][64]
#define OFF_WIH    173095936UL    // u16 [768][192]
#define OFF_WHH    173390848UL    // u16 [768][192]
#define OFF_WF1    173685760UL    // u16 [256][1536]
#define OFF_BSUM   174472192UL    // f32 [768]  (bih+bhh)

// ---------------- prep: board conversion + all weight conversions, one launch -------
__global__ void __launch_bounds__(256) prep(
    const float* __restrict__ board, u16* __restrict__ A_bf,
    const float* __restrict__ Wb1, const float* __restrict__ Wb2, const float* __restrict__ Wb3,
    const float* __restrict__ Wih, const float* __restrict__ Whh, const float* __restrict__ Wf1,
    const float* __restrict__ bih, const float* __restrict__ bhh,
    u16* __restrict__ dWb1, u16* __restrict__ dWb2, u16* __restrict__ dWb3,
    u16* __restrict__ dWih, u16* __restrict__ dWhh, u16* __restrict__ dWf1,
    float* __restrict__ bsum)
{
    int bid = blockIdx.x;
    if (bid < 61440) {
        // board: [10240][6075] f32 -> [10240][6144] bf16 (zero-padded)
        int row = bid / 6, chunk = bid - row * 6;
        int k0 = chunk * 1024 + threadIdx.x * 4;
        const float* s = board + (long)row * 6075 + k0;
        u16* d = A_bf + (long)row * 6144 + k0;
        if (k0 + 4 <= 6075) {
            float f0 = s[0], f1 = s[1], f2 = s[2], f3 = s[3];
            uint2 v;
            v.x = (unsigned)f2bf(f0) | ((unsigned)f2bf(f1) << 16);
            v.y = (unsigned)f2bf(f2) | ((unsigned)f2bf(f3) << 16);
            *(uint2*)d = v;
        } else {
#pragma unroll
            for (int z = 0; z < 4; ++z) {
                int k = k0 + z;
                d[z] = f2bf(k < 6075 ? s[z] : 0.f);
            }
        }
        return;
    }
    // weights: grid-stride over concatenated ranges with 2048 blocks
    const long C0 = 6291456, C1 = 6553600, C2 = 6586368, C3 = 6733824,
               C4 = 6881280, C5 = 7274496, C6 = 7275264;
    for (long i = (long)(bid - 61440) * 256 + threadIdx.x; i < C6; i += 2048L * 256) {
        if (i < C0) {
            int r = (int)(i / 6144), k = (int)(i % 6144);
            dWb1[i] = f2bf(k < 6075 ? Wb1[(long)r * 6075 + k] : 0.f);
        } else if (i < C1) {
            long j = i - C0;
            dWb2[j] = f2bf(Wb2[j]);
        } else if (i < C2) {
            long j = i - C1;
            dWb3[j] = f2bf(j < 16384 ? Wb3[j] : 0.f);
        } else if (i < C3) {
            long j = i - C2;
            dWih[j] = f2bf(Wih[j]);
        } else if (i < C4) {
            long j = i - C3;
            dWhh[j] = f2bf(Whh[j]);
        } else if (i < C5) {
            long j = i - C4;
            dWf1[j] = f2bf(Wf1[j]);
        } else {
            long j = i - C5;
            bsum[j] = bih[j] + bhh[j];
        }
    }
}

// ---------------- L1 GEMM: BM=160 x BN=128, 256 thr (4 waves, 80x64 each) -----------
// grid 512 = 2 blocks/CU. XCD mapping: all 8 column-blocks of a row-tile on the SAME
// XCD (bid%8 = rowt%8) -> shared A-panel slice L2-resident; B re-reads are L3-hits.
#define G160_LDS 73728
__global__ void __launch_bounds__(256, 2)
gemm160(const u16* __restrict__ A, const u16* __restrict__ B,
        const float* __restrict__ bias, u16* __restrict__ C, int K)
{
    extern __shared__ __align__(16) u16 smem[];   // [2][A 160x64 | B 128x64]
    const int tid = threadIdx.x, wv = tid >> 6, lane = tid & 63;
    const int bid = blockIdx.x;
    const int k8 = bid & 7;
    const int j  = bid >> 3;
    const int rowt = k8 + (j >> 3) * 8;
    const int col  = j & 7;
    const long m0 = (long)rowt * 160;
    const long n0 = (long)col * 128;

    const int sr8 = lane >> 3;
    const int sslot = (lane & 7) ^ sr8;
    const u16* Ag = A + (m0 + wv * 8 + sr8) * (long)K + sslot * 8;
    const u16* Bg = B + (n0 + wv * 8 + sr8) * (long)K + sslot * 8;
    const int wr = wv >> 1, wc = wv & 1;
    const int wm = wr * 80, wn = wc * 64;
    const int fr = lane & 15, hi = lane >> 4, fx = fr & 7;

    const int nk = K >> 6;
    v4f acc[5][4] = {};

    auto STAGE = [&](int buf, int t) {
        const long k0 = (long)t * 64;
        const int ab = buf * 18432;
#pragma unroll
        for (int r = 0; r < 5; ++r)
            gload(Ag + (long)r * 32 * K + k0, smem + ab + r * 2048 + wv * 512);
#pragma unroll
        for (int r = 0; r < 4; ++r)
            gload(Bg + (long)r * 32 * K + k0, smem + ab + 10240 + r * 2048 + wv * 512);
    };
    auto LDA_ = [&](int buf, int ks, int i) -> v8bf {
        return *(const v8bf*)(smem + buf * 18432 + (wm + i * 16 + fr) * 64 + ((ks * 4 + hi) ^ fx) * 8);
    };
    auto LDB_ = [&](int buf, int ks, int j2) -> v8bf {
        return *(const v8bf*)(smem + buf * 18432 + 10240 + (wn + j2 * 16 + fr) * 64 + ((ks * 4 + hi) ^ fx) * 8);
    };

    STAGE(0, 0);
    STAGE(1, 1);
    for (int t = 0; t < nk; ++t) {
        const int buf = t & 1;
        if (t + 1 < nk) { asm volatile("s_waitcnt vmcnt(9)" ::: "memory"); }
        else            { asm volatile("s_waitcnt vmcnt(0)" ::: "memory"); }
        asm volatile("s_barrier" ::: "memory");
        __builtin_amdgcn_s_setprio(1);
        v8bf a0[5], a1[5], b0[4], b1[4];
#pragma unroll
        for (int j2 = 0; j2 < 4; ++j2) b0[j2] = LDB_(buf, 0, j2);
#pragma unroll
        for (int i = 0; i < 5; ++i) a0[i] = LDA_(buf, 0, i);
        __builtin_amdgcn_sched_barrier(0);
#pragma unroll
        for (int j2 = 0; j2 < 4; ++j2) b1[j2] = LDB_(buf, 1, j2);
#pragma unroll
        for (int i = 0; i < 5; ++i) a1[i] = LDA_(buf, 1, i);
#pragma unroll
        for (int i = 0; i < 5; ++i)
#pragma unroll
            for (int j2 = 0; j2 < 4; ++j2)
                acc[i][j2] = __builtin_amdgcn_mfma_f32_16x16x32_bf16(a0[i], b0[j2], acc[i][j2], 0, 0, 0);
        __builtin_amdgcn_sched_barrier(0);
        __builtin_amdgcn_s_setprio(0);
        asm volatile("s_waitcnt lgkmcnt(0)" ::: "memory");
        __builtin_amdgcn_sched_barrier(0);
        asm volatile("s_barrier" ::: "memory");
        if (t + 2 < nk) STAGE(buf, t + 2);
        __builtin_amdgcn_s_setprio(1);
#pragma unroll
        for (int i = 0; i < 5; ++i)
#pragma unroll
            for (int j2 = 0; j2 < 4; ++j2)
                acc[i][j2] = __builtin_amdgcn_mfma_f32_16x16x32_bf16(a1[i], b1[j2], acc[i][j2], 0, 0, 0);
        __builtin_amdgcn_s_setprio(0);
    }

#pragma unroll
    for (int i = 0; i < 5; ++i) {
        const long mr = m0 + wm + i * 16 + hi * 4;
#pragma unroll
        for (int j2 = 0; j2 < 4; ++j2) {
            const long n = n0 + wn + j2 * 16 + fr;
            float bv = bias[n];
#pragma unroll
            for (int r = 0; r < 4; ++r) {
                float v = fmaxf(acc[i][j2][r] + bv, 0.f);
                C[(mr + r) * 1024L + n] = f2bf(v);
            }
        }
    }
}

// ---------------- L2 GEMM (BM=64 BN=256 K=1024) with fused L3 epilogue --------------
#define L23_LDS 81920
__global__ void __launch_bounds__(512, 1)
gemm_l23(const u16* __restrict__ A, const u16* __restrict__ B, const float* __restrict__ b2,
         const u16* __restrict__ W3, const float* __restrict__ b3, float* __restrict__ Out)
{
    extern __shared__ __align__(16) u16 smem[];   // [2][A 64x64 | B 256x64]
    const int tid = threadIdx.x, wv = tid >> 6, lane = tid & 63;
    const long m0 = (long)blockIdx.x * 64;
    const int sr8 = lane >> 3;
    const int sslot = (lane & 7) ^ sr8;
    const u16* Ag = A + (m0 + wv * 8 + sr8) * 1024L + sslot * 8;
    const u16* Bg = B + (wv * 8 + sr8) * 1024L + sslot * 8;
    const int wr = wv >> 2, wc = wv & 3;
    const int wm = wr * 32, wn = wc * 64;
    const int fr = lane & 15, hi = lane >> 4, fx = fr & 7;

    v4f acc[2][4] = {};

    auto STAGE = [&](int buf, int t) {
        const long k0 = (long)t * 64;
        const int ab = buf * 20480;
        gload(Ag + k0, smem + ab + wv * 512);
#pragma unroll
        for (int r = 0; r < 4; ++r)
            gload(Bg + (long)r * 64 * 1024 + k0, smem + ab + 4096 + r * 4096 + wv * 512);
    };
    auto COMPUTE = [&](int buf) {
#pragma unroll
        for (int ks = 0; ks < 2; ++ks) {
            const int sw = ((ks * 4 + hi) ^ fx) * 8;
            v8bf a[2], b[4];
#pragma unroll
            for (int i = 0; i < 2; ++i)
                a[i] = *(const v8bf*)(smem + buf * 20480 + (wm + i * 16 + fr) * 64 + sw);
#pragma unroll
            for (int j = 0; j < 4; ++j)
                b[j] = *(const v8bf*)(smem + buf * 20480 + 4096 + (wn + j * 16 + fr) * 64 + sw);
#pragma unroll
            for (int i = 0; i < 2; ++i)
#pragma unroll
                for (int j = 0; j < 4; ++j)
                    acc[i][j] = __builtin_amdgcn_mfma_f32_16x16x32_bf16(a[i], b[j], acc[i][j], 0, 0, 0);
        }
    };

    STAGE(0, 0);
    __syncthreads();
    int t = 1;
    while (true) {
        if (t < 16) STAGE(1, t);
        COMPUTE(0);
        if (t >= 16) break;
        __syncthreads();
        ++t;
        if (t < 16) STAGE(0, t);
        COMPUTE(1);
        if (t >= 16) break;
        __syncthreads();
        ++t;
    }
    __syncthreads();
    u16* C2s = smem;
#pragma unroll
    for (int i = 0; i < 2; ++i) {
        const int rrow = wm + i * 16 + hi * 4;
#pragma unroll
        for (int j = 0; j < 4; ++j) {
            const int ccol = wn + j * 16 + fr;
            float bv = b2[ccol];
#pragma unroll
            for (int r = 0; r < 4; ++r)
                C2s[(rrow + r) * 264 + ccol] = f2bf(fmaxf(acc[i][j][r] + bv, 0.f));
        }
    }
    __syncthreads();
    if (wv < 4) {
        v4f a3[4] = {};
#pragma unroll
        for (int kk = 0; kk < 8; ++kk) {
            v8bf af = *(const v8bf*)(&C2s[(wv * 16 + fr) * 264 + kk * 32 + hi * 8]);
#pragma unroll
            for (int j = 0; j < 4; ++j) {
                v8bf bfr = *(const v8bf*)(W3 + (j * 16 + fr) * 256 + kk * 32 + hi * 8);
                a3[j] = __builtin_amdgcn_mfma_f32_16x16x32_bf16(af, bfr, a3[j], 0, 0, 0);
            }
        }
#pragma unroll
        for (int j = 0; j < 4; ++j) {
            int n = j * 16 + fr;
            float bv = b3[n];
#pragma unroll
            for (int q = 0; q < 4; ++q)
                Out[(m0 + wv * 16 + hi * 4 + q) * 64 + n] = a3[j][q] + bv;
        }
    }
}

// ---------------- small 3-layer MLP body (order/message), f32, LDS-resident ----------
template<int D0, int D1>
__device__ __forceinline__ void mlp3_body(
    float* sm, const float* __restrict__ X,
    const float* __restrict__ W1, const float* __restrict__ B1,
    const float* __restrict__ W2, const float* __restrict__ B2,
    const float* __restrict__ W3, const float* __restrict__ B3,
    float* __restrict__ Out, int blk)
{
    float* w1s = sm;
    float* w2s = w1s + D0 * D1;
    float* w3s = w2s + D1 * 32;
    float* b1s = w3s + 32 * 64;
    float* b2s = b1s + D1;
    float* b3s = b2s + 32;
    float* xs  = b3s + 64;
    float* h1  = xs + 32 * D0;
    float* h2  = h1 + 32 * D1;

    const int tid = threadIdx.x;
    const long row0 = (long)blk * 32;

    for (int i = tid; i < D0 * D1; i += 256) { int k = i / D1, n = i % D1; w1s[i] = W1[n * D0 + k]; }
    for (int i = tid; i < D1 * 32; i += 256) { int k = i / 32,  n = i % 32; w2s[i] = W2[n * D1 + k]; }
    for (int i = tid; i < 32 * 64; i += 256) { int k = i / 64,  n = i % 64; w3s[i] = W3[n * 32 + k]; }
    if (tid < D1) b1s[tid] = B1[tid];
    if (tid < 32) b2s[tid] = B2[tid];
    if (tid < 64) b3s[tid] = B3[tid];
    for (int i = tid; i < 32 * D0; i += 256) xs[i] = X[(row0 + i / D0) * D0 + i % D0];
    __syncthreads();

    const int wv = tid >> 6, lane = tid & 63;
    const int r0 = wv * 8;
    {
        constexpr int NL = D1 / 64;
        float acc[NL][8];
#pragma unroll
        for (int a = 0; a < NL; ++a)
#pragma unroll
            for (int r = 0; r < 8; ++r) acc[a][r] = 0.f;
        for (int k = 0; k < D0; ++k) {
            float w[NL];
#pragma unroll
            for (int a = 0; a < NL; ++a) w[a] = w1s[k * D1 + lane + a * 64];
#pragma unroll
            for (int r = 0; r < 8; ++r) {
                float x = xs[(r0 + r) * D0 + k];
#pragma unroll
                for (int a = 0; a < NL; ++a) acc[a][r] += w[a] * x;
            }
        }
#pragma unroll
        for (int a = 0; a < NL; ++a)
#pragma unroll
            for (int r = 0; r < 8; ++r)
                h1[(r0 + r) * D1 + lane + a * 64] = fmaxf(acc[a][r] + b1s[lane + a * 64], 0.f);
    }
    __syncthreads();
    {
        int n = lane & 31;
        int rb = r0 + (lane >> 5) * 4;
        float acc[4] = {0, 0, 0, 0};
        for (int k = 0; k < D1; ++k) {
            float w = w2s[k * 32 + n];
#pragma unroll
            for (int r = 0; r < 4; ++r) acc[r] += w * h1[(rb + r) * D1 + k];
        }
#pragma unroll
        for (int r = 0; r < 4; ++r) h2[(rb + r) * 32 + n] = fmaxf(acc[r] + b2s[n], 0.f);
    }
    __syncthreads();
    {
        float acc[8] = {};
        for (int k = 0; k < 32; ++k) {
            float w = w3s[k * 64 + lane];
#pragma unroll
            for (int r = 0; r < 8; ++r) acc[r] += w * h2[(r0 + r) * 32 + k];
        }
#pragma unroll
        for (int r = 0; r < 8; ++r) Out[(row0 + r0 + r) * 64 + lane] = acc[r] + b3s[lane];
    }
}

#define MLP_LDS 71552
__global__ void __launch_bounds__(256)
mlp3_dual(const float* __restrict__ Xo,
          const float* __restrict__ Wo1, const float* __restrict__ bo1,
          const float* __restrict__ Wo2, const float* __restrict__ bo2,
          const float* __restrict__ Wo3, const float* __restrict__ bo3,
          float* __restrict__ ofe,
          const float* __restrict__ Xm,
          const float* __restrict__ Wm1, const float* __restrict__ bm1,
          const float* __restrict__ Wm2, const float* __restrict__ bm2,
          const float* __restrict__ Wm3, const float* __restrict__ bm3,
          float* __restrict__ mfe)
{
    extern __shared__ __align__(16) float sm[];
    if (blockIdx.x < 320)
        mlp3_body<40, 128>(sm, Xo, Wo1, bo1, Wo2, bo2, Wo3, bo3, ofe, blockIdx.x);
    else
        mlp3_body<20, 64>(sm, Xm, Wm1, bm1, Wm2, bm2, Wm3, bm3, mfe, blockIdx.x - 320);
}

// ---------------- build_xg: scramble + BN stats + relu -> xin (LDS) -> Xg GEMM -------
// One block per (p,s). xin never touches global; Xg = xin @ Wih^T + bsum computed
// in-block via MFMA (Wih L2-hot across 80 blocks). Replaces build_xin2 + Xg GEMM.
// LDS: f32 staging 98304 + stats 2048pad -> xin bf16 [128][192] swizzled at 100352.
#define BXG_LDS 149504
__global__ void __launch_bounds__(256, 1)
build_xg(const float* __restrict__ bfe, const float* __restrict__ ofe, const float* __restrict__ mfe,
         const float* __restrict__ g1, const float* __restrict__ be1,
         const float* __restrict__ g2, const float* __restrict__ be2,
         const float* __restrict__ g3, const float* __restrict__ be3,
         const u16* __restrict__ Wih, const float* __restrict__ bsum,
         float* __restrict__ Xg)
{
    extern __shared__ __align__(16) float ls[];   // [3][128][8][8]
    float* coefA = ls + 24576;
    float* coefB = coefA + 24;
    float* psum  = coefB + 24;
    float* psum2 = psum + 192;
    u16* xs16 = (u16*)((char*)ls + 100352);       // [128][192] bf16, 16B-slot swizzled
    const int p = blockIdx.x >> 3, s = blockIdx.x & 7;
    const int tid = threadIdx.x;
    const float* Fs[3] = {bfe, ofe, mfe};
    for (int g = tid; g < 3072; g += 256) {
        int br = g >> 10, rr = g & 1023, bb = rr >> 3, tt = rr & 7;
        const float* srcp = Fs[br] + ((long)(bb * 80 + p * 8 + tt)) * 64 + s * 8;
        float4 v0 = *(const float4*)srcp;
        float4 v1 = *(const float4*)(srcp + 4);
        *(float4*)(ls + (long)g * 8) = v0;
        *(float4*)(ls + (long)g * 8 + 4) = v1;
    }
    __syncthreads();
    if (tid < 192) {
        int pair = tid >> 3, part = tid & 7;
        int br = pair >> 3, cl = pair & 7;
        float s1 = 0.f, s2 = 0.f;
        for (int b2 = 0; b2 < 16; ++b2) {
            int bb = part * 16 + b2;
            const float* base = ls + ((br * 128 + bb) * 8) * 8 + cl;
#pragma unroll
            for (int tt = 0; tt < 8; ++tt) { float v = base[tt * 8]; s1 += v; s2 += v * v; }
        }
        psum[tid] = s1; psum2[tid] = s2;
    }
    __syncthreads();
    if (tid < 24) {
        float s1 = 0.f, s2 = 0.f;
#pragma unroll
        for (int q = 0; q < 8; ++q) { s1 += psum[tid * 8 + q]; s2 += psum2[tid * 8 + q]; }
        int br = tid >> 3, cl = tid & 7, c = s * 8 + cl;
        const float* G  = br == 0 ? g1  : (br == 1 ? g2  : g3);
        const float* BE = br == 0 ? be1 : (br == 1 ? be2 : be3);
        float m  = s1 * (1.f / 1024.f);
        float var = s2 * (1.f / 1024.f) - m * m;
        float Aa = G[c] * rsqrtf(var + 1e-5f);
        coefA[tid] = Aa;
        coefB[tid] = BE[c] - Aa * m;
    }
    __syncthreads();
    {   // xin slice -> LDS (swizzled 16B slots: slot ^ (row&7))
        const int u = tid >> 1, h0 = (tid & 1) * 96;
        const int cl = u >> 4;
        const int ub = (u & 15) * 8;
        const int swr = u & 7;
        union { u16 u[8]; uint4 v; } pk;
        for (int hq = 0; hq < 12; ++hq) {
#pragma unroll
            for (int z = 0; z < 8; ++z) {
                int h = h0 + hq * 8 + z;
                int bb = ub + h / 24, t = h % 24, br = t >> 3, tt = t & 7;
                float v = ls[((br * 128 + bb) * 8 + tt) * 8 + cl];
                float r = fmaxf(v * coefA[br * 8 + cl] + coefB[br * 8 + cl], 0.f);
                pk.u[z] = f2bf(r);
            }
            int slot = (tid & 1) * 12 + hq;       // 0..23
            *(uint4*)(xs16 + u * 192 + ((slot ^ swr) * 8)) = pk.v;
        }
    }
    __syncthreads();
    // Xg = xin @ Wih^T + bsum for this block's 128 rows. Wave wv owns cols [wv*192, +192).
    const int wv = tid >> 6, lane = tid & 63;
    const int fr = lane & 15, hi = lane >> 4;
    const long R0 = (long)blockIdx.x * 128;
    for (int nf = 0; nf < 12; ++nf) {
        const int n = wv * 192 + nf * 16 + fr;
        v8bf w[6];
#pragma unroll
        for (int k = 0; k < 6; ++k)
            w[k] = *(const v8bf*)(Wih + (long)n * 192 + k * 32 + hi * 8);
        float bv = bsum[n];
#pragma unroll
        for (int mf = 0; mf < 8; ++mf) {
            const int r = mf * 16 + fr;
            v4f acc = {};
#pragma unroll
            for (int k = 0; k < 6; ++k) {
                v8bf a = *(const v8bf*)(xs16 + r * 192 + (((k * 4 + hi) ^ (r & 7)) * 8));
                acc = __builtin_amdgcn_mfma_f32_16x16x32_bf16(a, w[k], acc, 0, 0, 0);
            }
#pragma unroll
            for (int q = 0; q < 4; ++q)
                Xg[(R0 + mf * 16 + hi * 4 + q) * 768 + n] = acc[q] + bv;
        }
    }
}

// ---------------- persistent LSTM + fused Wf1: 160 blocks x 8 rows --------------------
#define LSTM_LDS (6400 + 24576)
__global__ void __launch_bounds__(512, 1)
lstm_persist(const float* __restrict__ Xg, const u16* __restrict__ Whh,
             const float* __restrict__ h0, const float* __restrict__ c0,
             const u16* __restrict__ Wf1, const float* __restrict__ bf1,
             float* __restrict__ fc1o)
{
    extern __shared__ __align__(16) u16 smem[];
    u16*   hS    = smem;                          // [16][200] (rows 8-15 zero)
    float* gates = (float*)(smem + 16 * 200);     // [8][768]

    const int tid = threadIdx.x, wv = tid >> 6, lane = tid & 63;
    const int R0 = blockIdx.x * 8;
    const int fr = lane & 15, hi = lane >> 4;

    v8bf Wreg[6][6];
#pragma unroll
    for (int nt = 0; nt < 6; ++nt)
#pragma unroll
        for (int ks = 0; ks < 6; ++ks)
            Wreg[nt][ks] = *(const v8bf*)(Whh + (long)(nt * 128 + wv * 16 + fr) * 192 + ks * 32 + hi * 8);

    for (int i = tid; i < 16 * 200; i += 512) {
        int r = i / 200, cx = i % 200;
        u16 v = 0;
        if (r < 8 && cx < 192) v = f2bf(h0[(R0 + r) * 192 + cx]);
        hS[i] = v;
    }
    float creg[3];
#pragma unroll
    for (int j = 0; j < 3; ++j) {
        int e = j * 512 + tid;
        creg[j] = c0[(R0 + e / 192) * 192 + e % 192];
    }

    v4f f1acc[2] = {};
    const int nb0 = wv * 32;
    auto WF1ACC = [&](int ss, const v8bf* a) {
#pragma unroll
        for (int jf = 0; jf < 2; ++jf) {
            v4f tacc = f1acc[jf];
#pragma unroll
            for (int ks = 0; ks < 6; ++ks) {
                v8bf bfr = *(const v8bf*)(Wf1 + (long)(nb0 + jf * 16 + fr) * 1536 + ss * 192 + ks * 32 + hi * 8);
                tacc = __builtin_amdgcn_mfma_f32_16x16x32_bf16(a[ks], bfr, tacc, 0, 0, 0);
            }
            f1acc[jf] = tacc;
        }
    };

    for (int s = 0; s < 8; ++s) {
        __syncthreads();
        v8bf a[6];
#pragma unroll
        for (int ks = 0; ks < 6; ++ks)
            a[ks] = *(const v8bf*)(&hS[fr * 200 + ks * 32 + hi * 8]);
        if (s > 0) WF1ACC(s - 1, a);
#pragma unroll
        for (int nt = 0; nt < 6; ++nt) {
            v4f acc = {};
#pragma unroll
            for (int ks = 0; ks < 6; ++ks)
                acc = __builtin_amdgcn_mfma_f32_16x16x32_bf16(a[ks], Wreg[nt][ks], acc, 0, 0, 0);
            int n = nt * 128 + wv * 16 + fr;
            if (hi < 2) {
#pragma unroll
                for (int q = 0; q < 4; ++q)
                    gates[(hi * 4 + q) * 768 + n] = acc[q];
            }
        }
        __syncthreads();
#pragma unroll
        for (int j = 0; j < 3; ++j) {
            int e = j * 512 + tid;
            int r = e / 192, hd = e % 192;
            int grow = R0 + r;
            int p = grow >> 7, u = grow & 127;
            long xrow = (long)((p * 8 + s) * 128 + u) * 768;
            float gi = Xg[xrow + hd]       + gates[r * 768 + hd];
            float gf = Xg[xrow + 192 + hd] + gates[r * 768 + 192 + hd];
            float gg = Xg[xrow + 384 + hd] + gates[r * 768 + 384 + hd];
            float go = Xg[xrow + 576 + hd] + gates[r * 768 + 576 + hd];
            float c = sigf(gf) * creg[j] + sigf(gi) * tanhf(gg);
            float h = sigf(go) * tanhf(c);
            creg[j] = c;
            hS[r * 200 + hd] = f2bf(h);
        }
    }
    __syncthreads();
    {
        v8bf a[6];
#pragma unroll
        for (int ks = 0; ks < 6; ++ks)
            a[ks] = *(const v8bf*)(&hS[fr * 200 + ks * 32 + hi * 8]);
        WF1ACC(7, a);
    }
    if (hi < 2) {
#pragma unroll
        for (int jf = 0; jf < 2; ++jf)
#pragma unroll
            for (int q = 0; q < 4; ++q) {
                int row = hi * 4 + q;
                int n = nb0 + jf * 16 + fr;
                fc1o[(long)(R0 + row) * 256 + n] = fmaxf(f1acc[jf][q] + bf1[n], 0.f);
            }
    }
}

// ---------------- final FC: one wave per (u, n), shuffle reduce ----------------
__global__ void __launch_bounds__(256) final_fc2(
    const float* __restrict__ fc1, const float* __restrict__ oi, const float* __restrict__ mi,
    const float* __restrict__ Wf2, const float* __restrict__ bf2, float* __restrict__ out)
{
    const int wv = threadIdx.x >> 6, lane = threadIdx.x & 63;
    const int w = blockIdx.x * 4 + wv;      // 0..1023
    const int u = w >> 3, n = w & 7;
    const float* wrow = Wf2 + n * 270;
    float wreg[4];
#pragma unroll
    for (int q = 0; q < 4; ++q) wreg[q] = wrow[lane + 64 * q];
    float wtail = (lane < 14) ? wrow[256 + lane] : 0.f;
    float acc = 0.f;
    for (int p = 0; p < 10; ++p) {
        const float* x = fc1 + (long)(p * 128 + u) * 256;
#pragma unroll
        for (int q = 0; q < 4; ++q) acc += x[lane + 64 * q] * wreg[q];
        float t = 0.f;
        if (lane < 7)       t = oi[(u * 10 + p) * 7 + lane];
        else if (lane < 14) t = mi[(u * 10 + p) * 7 + lane - 7];
        acc += t * wtail;
    }
#pragma unroll
    for (int off = 32; off; off >>= 1) acc += __shfl_xor(acc, off);
    if (lane == 0) out[u * 8 + n] = acc + bf2[n];
}

// ---------------- launcher ----------------
extern "C" void kernel_launch(void* const* d_in, const int* in_sizes, int n_in,
                              void* d_out, int out_size, void* d_ws, size_t ws_size,
                              hipStream_t stream)
{
    (void)in_sizes; (void)n_in; (void)out_size; (void)ws_size;
    const float* board = (const float*)d_in[0];
    const float* order = (const float*)d_in[1];
    const float* mess  = (const float*)d_in[2];
    const float* oi    = (const float*)d_in[3];
    const float* mi    = (const float*)d_in[4];
    const float* h0    = (const float*)d_in[5];
    const float* c0    = (const float*)d_in[6];
    const float* Wb1 = (const float*)d_in[7];  const float* bb1 = (const float*)d_in[8];
    const float* Wb2 = (const float*)d_in[9];  const float* bb2 = (const float*)d_in[10];
    const float* Wb3 = (const float*)d_in[11]; const float* bb3 = (const float*)d_in[12];
    const float* Wo1 = (const float*)d_in[13]; const float* bo1 = (const float*)d_in[14];
    const float* Wo2 = (const float*)d_in[15]; const float* bo2 = (const float*)d_in[16];
    const float* Wo3 = (const float*)d_in[17]; const float* bo3 = (const float*)d_in[18];
    const float* Wm1 = (const float*)d_in[19]; const float* bm1 = (const float*)d_in[20];
    const float* Wm2 = (const float*)d_in[21]; const float* bm2 = (const float*)d_in[22];
    const float* Wm3 = (const float*)d_in[23]; const float* bm3 = (const float*)d_in[24];
    const float* g1  = (const float*)d_in[25]; const float* be1 = (const float*)d_in[26];
    const float* g2  = (const float*)d_in[27]; const float* be2 = (const float*)d_in[28];
    const float* g3  = (const float*)d_in[29]; const float* be3 = (const float*)d_in[30];
    const float* Wih = (const float*)d_in[31]; const float* Whh = (const float*)d_in[32];
    const float* bih = (const float*)d_in[33]; const float* bhh = (const float*)d_in[34];
    const float* Wf1 = (const float*)d_in[35]; const float* bf1 = (const float*)d_in[36];
    const float* Wf2 = (const float*)d_in[37]; const float* bf2 = (const float*)d_in[38];

    uint8_t* ws = (uint8_t*)d_ws;
    u16*   A_bf    = (u16*)(ws + OFF_ABF);
    float* Xg      = (float*)(ws + OFF_XG);
    float* fc1o    = (float*)(ws + OFF_FC1);
    u16*   Wb1_bf  = (u16*)(ws + OFF_WB1);
    u16*   C1_bf   = (u16*)(ws + OFF_C1);
    u16*   Wb2_bf  = (u16*)(ws + OFF_WB2);
    u16*   Wb3_bf  = (u16*)(ws + OFF_WB3);
    float* bfe     = (float*)(ws + OFF_BFE);
    float* ofe     = (float*)(ws + OFF_OFE);
    float* mfe     = (float*)(ws + OFF_MFE);
    u16*   Wih_bf  = (u16*)(ws + OFF_WIH);
    u16*   Whh_bf  = (u16*)(ws + OFF_WHH);
    u16*   Wf1_bf  = (u16*)(ws + OFF_WF1);
    float* bsum    = (float*)(ws + OFF_BSUM);

    // 0) board + weight conversions, one launch
    prep<<<63488, 256, 0, stream>>>(board, A_bf, Wb1, Wb2, Wb3, Wih, Whh, Wf1, bih, bhh,
                                    Wb1_bf, Wb2_bf, Wb3_bf, Wih_bf, Whh_bf, Wf1_bf, bsum);

    // 1) board MLP: L1 then L2+L3 fused
    hipFuncSetAttribute(reinterpret_cast<const void*>(gemm160),
                        hipFuncAttributeMaxDynamicSharedMemorySize, G160_LDS);
    gemm160<<<512, 256, G160_LDS, stream>>>(A_bf, Wb1_bf, bb1, C1_bf, 6144);
    hipFuncSetAttribute(reinterpret_cast<const void*>(gemm_l23),
                        hipFuncAttributeMaxDynamicSharedMemorySize, L23_LDS);
    gemm_l23<<<160, 512, L23_LDS, stream>>>(C1_bf, Wb2_bf, bb2, Wb3_bf, bb3, bfe);

    // 2) order + message MLPs in one launch
    hipFuncSetAttribute(reinterpret_cast<const void*>(mlp3_dual),
                        hipFuncAttributeMaxDynamicSharedMemorySize, MLP_LDS);
    mlp3_dual<<<640, 256, MLP_LDS, stream>>>(order, Wo1, bo1, Wo2, bo2, Wo3, bo3, ofe,
                                             mess, Wm1, bm1, Wm2, bm2, Wm3, bm3, mfe);

    // 3) scramble + BN stats + xin(LDS) + Xg GEMM, one launch
    hipFuncSetAttribute(reinterpret_cast<const void*>(build_xg),
                        hipFuncAttributeMaxDynamicSharedMemorySize, BXG_LDS);
    build_xg<<<80, 256, BXG_LDS, stream>>>(bfe, ofe, mfe, g1, be1, g2, be2, g3, be3,
                                           Wih_bf, bsum, Xg);

    // 4) recurrence + fused Wf1/bias/relu (Whh in registers, 160 blocks x 8 rows)
    hipFuncSetAttribute(reinterpret_cast<const void*>(lstm_persist),
                        hipFuncAttributeMaxDynamicSharedMemorySize, LSTM_LDS);
    lstm_persist<<<160, 512, LSTM_LDS, stream>>>(Xg, Whh_bf, h0, c0, Wf1_bf, bf1, fc1o);

    // 5) final
    final_fc2<<<256, 256, 0, stream>>>(fc1o, oi, mi, Wf2, bf2, (float*)d_out);
}